// Round 12
// baseline (271.470 us; speedup 1.0000x reference)
//
#include <hip/hip_runtime.h>
#include <hip/hip_bf16.h>
#include <math.h>

typedef __bf16 bf16x8 __attribute__((ext_vector_type(8)));
typedef __bf16 bf16x4 __attribute__((ext_vector_type(4)));
typedef float  f32x4  __attribute__((ext_vector_type(4)));

#define T_SEQ 2048
#define NH    16
#define HD    64
#define DM    1024
// softmax logits pre-scaled by 1/sqrt(64) * log2(e) so we can use exp2
#define QSCALE 0.18033688011112043f

__device__ __forceinline__ f32x4 mfma16(bf16x8 a, bf16x8 b, f32x4 c) {
    return __builtin_amdgcn_mfma_f32_16x16x32_bf16(a, b, c, 0, 0, 0);
}

// async global->LDS, 16B per lane. LDS dest is wave-uniform base + lane*16
// (our staging layout is exactly that). Barrier's implicit vmcnt(0) drains.
__device__ __forceinline__ void gl2lds(const void* g, void* l) {
    __builtin_amdgcn_global_load_lds(
        (const __attribute__((address_space(1))) void*)g,
        (__attribute__((address_space(3))) void*)l, 16, 0, 0);
}

// ================= prep (one dispatch) =================
__device__ __forceinline__ void tsplit_body(const float* __restrict__ in,
                                            __bf16* __restrict__ oh, __bf16* __restrict__ ol,
                                            int K, int N, int n0, int k0, int SPLIT,
                                            float* tile /* [64][65] LDS */)
{
    const int tid = threadIdx.x;
#pragma unroll
    for (int it = 0; it < 2; ++it) {
        int r = it * 32 + (tid >> 3), c8 = (tid & 7) * 8;
        f32x4 a0 = *(const f32x4*)&in[(size_t)(k0 + r) * N + n0 + c8];
        f32x4 a1 = *(const f32x4*)&in[(size_t)(k0 + r) * N + n0 + c8 + 4];
#pragma unroll
        for (int j = 0; j < 4; ++j) { tile[r * 65 + c8 + j] = a0[j]; tile[r * 65 + c8 + 4 + j] = a1[j]; }
    }
    __syncthreads();
    const int n = tid >> 2, kb = (tid & 3) * 16;
    bf16x8 h0, h1, l0, l1;
#pragma unroll
    for (int j = 0; j < 8; ++j) {
        float v0 = tile[(kb + j) * 65 + n], v1 = tile[(kb + 8 + j) * 65 + n];
        __bf16 hb0 = (__bf16)v0, hb1 = (__bf16)v1;
        h0[j] = hb0; h1[j] = hb1;
        if (SPLIT) { l0[j] = (__bf16)(v0 - (float)hb0); l1[j] = (__bf16)(v1 - (float)hb1); }
    }
    size_t o = (size_t)(n0 + n) * K + k0 + kb;
    *(bf16x8*)&oh[o] = h0; *(bf16x8*)&oh[o + 8] = h1;
    if (SPLIT) { *(bf16x8*)&ol[o] = l0; *(bf16x8*)&ol[o + 8] = l1; }
}

__global__ __launch_bounds__(256)
void prep(const float* __restrict__ x, const float* __restrict__ Wq,
          const float* __restrict__ Wkv, const float* __restrict__ Wv,
          const float* __restrict__ Wo, const float* __restrict__ Wk,
          const float* __restrict__ Wkr, const float* __restrict__ bk,
          __bf16* xh, __bf16* xl, __bf16* Wqt_h, __bf16* Wqt_l,
          __bf16* Wkvt_h, __bf16* Wkvt_l, __bf16* Wvt, __bf16* Wot,
          __bf16* W2th, __bf16* W2tl, float* b2)
{
    __shared__ float tile[64 * 65];
    const int g = blockIdx.x, tid = threadIdx.x;
    if (g < 2048) {                       // split x -> xh/xl
        size_t idx = ((size_t)g * 256 + tid) * 8;
        f32x4 a0 = *(const f32x4*)&x[idx];
        f32x4 a1 = *(const f32x4*)&x[idx + 4];
        bf16x8 h, l;
#pragma unroll
        for (int j = 0; j < 4; ++j) {
            __bf16 h0 = (__bf16)a0[j];
            h[j]     = h0; l[j]     = (__bf16)(a0[j] - (float)h0);
            __bf16 h1 = (__bf16)a1[j];
            h[4 + j] = h1; l[4 + j] = (__bf16)(a1[j] - (float)h1);
        }
        *(bf16x8*)&xh[idx] = h;
        *(bf16x8*)&xl[idx] = l;
    } else if (g < 2304) {                // Wq -> [N,K] split
        int i = g - 2048;
        tsplit_body(Wq, Wqt_h, Wqt_l, 1024, 1024, (i & 15) * 64, (i >> 4) * 64, 1, tile);
    } else if (g < 2368) {                // Wkv -> split
        int i = g - 2304;
        tsplit_body(Wkv, Wkvt_h, Wkvt_l, 1024, 256, (i & 3) * 64, (i >> 2) * 64, 1, tile);
    } else if (g < 2432) {                // Wv -> trunc
        int i = g - 2368;
        tsplit_body(Wv, Wvt, nullptr, 256, 1024, (i & 15) * 64, (i >> 4) * 64, 0, tile);
    } else if (g < 2688) {                // Wo -> trunc
        int i = g - 2432;
        tsplit_body(Wo, Wot, nullptr, 1024, 1024, (i & 15) * 64, (i >> 4) * 64, 0, tile);
    } else {                              // W2 = Wk_h @ Wkr (transposed split) + b2
        int o    = (g - 2688) * 256 + tid;
        int rowk = o >> 10, col = o & 1023;
        int h = col >> 6, d = col & 63;
        float acc = 0.0f;
        if (rowk < 256) {
#pragma unroll 8
            for (int j = 0; j < 64; ++j)
                acc += Wk[(size_t)rowk * DM + h * HD + j] * Wkr[j * HD + d];
            __bf16 hb = (__bf16)acc;
            W2th[(size_t)col * 256 + rowk] = hb;
            W2tl[(size_t)col * 256 + rowk] = (__bf16)(acc - (float)hb);
        } else {
#pragma unroll 8
            for (int j = 0; j < 64; ++j)
                acc += bk[h * HD + j] * Wkr[j * HD + d];
            b2[col] = acc;
        }
    }
}

// ================= 128x128-tile GEMM, async-pipelined K-loop =================
// A bf16 [M,K] (hi + optional lo), B bf16 [N,K] (hi + optional lo)
// OUTM: 0 bf16 | 1 fp32 | 2 dual split bf16
// EPI:  0 bias | 1 RoPE*QSCALE split-out | 2 bias then *t | 3 v->vtg transpose
// K-loop: DOUBLE-BUFFERED gl2lds panels, ONE barrier per 32-K step:
//   barrier; issue gl2lds(step j+1 -> buf^1); compute(buf)
// LDS layout per buf (32768 B): Ah @0, Al @8192, Bh @16384, Bl @24576.
// NOTE: never pass nullptr for a lo pointer with DUAL*=1 (r5-r7 bug).
// NOTE: branches of ONE dispatch must never write memory another branch reads
// (r9 bug: v wrote vtg overlaying xlo read by q). q+kv / k+v merges are safe.
// NOTE r4: 128x64 retile of gemm_o REGRESSED (+9 µs): fewer MFMA per LDS
// B-read + 2x barriers + cross-block LDS bank contention beat the occupancy
// gain. Keep fat 128x128 tiles even at 1 block/CU.
template <int DUALA, int DUALB, int OUTM, int EPI>
__device__ __forceinline__
void gemm_body(char* smem,
               const __bf16* __restrict__ Ahi, const __bf16* __restrict__ Alo,
               const __bf16* __restrict__ Bhi, const __bf16* __restrict__ Blo,
               const float* __restrict__ bias, void* __restrict__ Cp,
               void* __restrict__ Cp2, int m0, int n0, int N, int K)
{
    const int tid  = threadIdx.x;
    const int w    = tid >> 6;
    const int lane = tid & 63;
    const int l16  = lane & 15;
    const int quad = lane >> 4;
    const int wy   = w >> 1, wx = w & 1;

    f32x4 acc[4][4];
#pragma unroll
    for (int i = 0; i < 4; ++i)
#pragma unroll
        for (int j = 0; j < 4; ++j) acc[i][j] = (f32x4)0.0f;

    auto stage = [&](int k0, int buf) {
        char* bb = smem + buf * 32768;
#pragma unroll
        for (int i = 0; i < 2; ++i) {
            int s = i * 256 + tid, row = s >> 2, c8 = (s & 3) * 8;
            size_t aoff = (size_t)(m0 + row) * K + k0 + c8;
            size_t boff = (size_t)(n0 + row) * K + k0 + c8;
            char*  dst  = bb + (row * 32 + c8) * 2;
            gl2lds(&Ahi[aoff], dst);
            if (DUALA) gl2lds(&Alo[aoff], dst + 8192);
            gl2lds(&Bhi[boff], dst + 16384);
            if (DUALB) gl2lds(&Blo[boff], dst + 24576);
        }
    };

    stage(0, 0);
    const int J = K >> 5;
    for (int j = 0; j < J; ++j) {
        __syncthreads();               // drains gl2lds for step j (all waves)
        if (j + 1 < J) stage((j + 1) << 5, (j + 1) & 1);   // overlaps compute

        const __bf16* Ah = (const __bf16*)(smem + (j & 1) * 32768);
        const __bf16* Al = Ah + 4096;
        const __bf16* Bh = Ah + 8192;
        const __bf16* Bl = Ah + 12288;

        bf16x8 bfh[4], bfl[4];
#pragma unroll
        for (int ct = 0; ct < 4; ++ct) {
            bfh[ct] = *(const bf16x8*)&Bh[(wx * 64 + ct * 16 + l16) * 32 + quad * 8];
            if (DUALB) bfl[ct] = *(const bf16x8*)&Bl[(wx * 64 + ct * 16 + l16) * 32 + quad * 8];
        }
#pragma unroll
        for (int mf = 0; mf < 4; ++mf) {
            bf16x8 ah = *(const bf16x8*)&Ah[(wy * 64 + mf * 16 + l16) * 32 + quad * 8];
            bf16x8 al;
            if (DUALA) al = *(const bf16x8*)&Al[(wy * 64 + mf * 16 + l16) * 32 + quad * 8];
#pragma unroll
            for (int ct = 0; ct < 4; ++ct) {
                acc[mf][ct] = mfma16(ah, bfh[ct], acc[mf][ct]);
                if (DUALA) acc[mf][ct] = mfma16(al, bfh[ct], acc[mf][ct]);
                if (DUALB) acc[mf][ct] = mfma16(ah, bfl[ct], acc[mf][ct]);
            }
        }
    }

    float bias_v[4];
#pragma unroll
    for (int ct = 0; ct < 4; ++ct)
        bias_v[ct] = bias ? bias[n0 + wx * 64 + ct * 16 + l16] : 0.0f;

    if (EPI == 1) {  // RoPE (q): pair (d, d+32) = (ct, ct+2); *QSCALE; split out
        __bf16* Chi = (__bf16*)Cp;
        __bf16* Clo = (__bf16*)Cp2;
#pragma unroll
        for (int mf = 0; mf < 4; ++mf) {
#pragma unroll
            for (int r = 0; r < 4; ++r) {
                int   m = m0 + wy * 64 + mf * 16 + quad * 4 + r;
                float t = (float)(m & (T_SEQ - 1));
#pragma unroll
                for (int ct = 0; ct < 2; ++ct) {
                    int   d   = ct * 16 + l16;
                    float inv = powf(10000.0f, -(float)d * (1.0f / 32.0f));
                    float sv, cv;
                    sincosf(t * inv, &sv, &cv);
                    float lo = acc[mf][ct][r]     + bias_v[ct];
                    float hi = acc[mf][ct + 2][r] + bias_v[ct + 2];
                    float v0 = (lo * cv - hi * sv) * QSCALE;
                    float v1 = (hi * cv + lo * sv) * QSCALE;
                    size_t i0 = (size_t)m * N + n0 + wx * 64 + d;
                    size_t i1 = i0 + 32;
                    __bf16 h0 = (__bf16)v0, h1 = (__bf16)v1;
                    Chi[i0] = h0; Clo[i0] = (__bf16)(v0 - (float)h0);
                    Chi[i1] = h1; Clo[i1] = (__bf16)(v1 - (float)h1);
                }
            }
        }
    } else if (EPI == 3) {  // v: write vtg[bh][d][t] via per-wave LDS transpose
        __syncthreads();
        __bf16* vt = (__bf16*)(smem + w * 9216);   // [64][72]
#pragma unroll
        for (int mf = 0; mf < 4; ++mf)
#pragma unroll
            for (int ct = 0; ct < 4; ++ct)
#pragma unroll
                for (int r = 0; r < 4; ++r)
                    vt[(ct * 16 + l16) * 72 + mf * 16 + quad * 4 + r] =
                        (__bf16)(acc[mf][ct][r] + bias_v[ct]);
        const int bb   = m0 >> 11;
        const int head = (n0 + wx * 64) >> 6;
        const int bh   = bb * 16 + head;
        __bf16* out    = (__bf16*)Cp;
        size_t  gbase  = ((size_t)(bh * 64 + lane)) * T_SEQ + (m0 & (T_SEQ - 1)) + wy * 64;
#pragma unroll
        for (int j8 = 0; j8 < 8; ++j8)
            *(bf16x8*)&out[gbase + j8 * 8] = *(const bf16x8*)&vt[lane * 72 + j8 * 8];
    } else {
#pragma unroll
        for (int mf = 0; mf < 4; ++mf) {
#pragma unroll
            for (int r = 0; r < 4; ++r) {
                int   m     = m0 + wy * 64 + mf * 16 + quad * 4 + r;
                float scale = (EPI == 2) ? (float)(m & (T_SEQ - 1)) : 1.0f;
#pragma unroll
                for (int ct = 0; ct < 4; ++ct) {
                    float  v   = (acc[mf][ct][r] + bias_v[ct]) * scale;
                    size_t idx = (size_t)m * N + n0 + wx * 64 + ct * 16 + l16;
                    if (OUTM == 1)      ((float*)Cp)[idx]  = v;
                    else if (OUTM == 0) ((__bf16*)Cp)[idx] = (__bf16)v;
                    else {
                        __bf16 hb = (__bf16)v;
                        ((__bf16*)Cp)[idx]  = hb;
                        ((__bf16*)Cp2)[idx] = (__bf16)(v - (float)hb);
                    }
                }
            }
        }
    }
}

// merged kv + q gemm: grid (10, 32) = 320 blocks (kv first so it fills early)
__global__ __launch_bounds__(256)
void gemm_qkv(const __bf16* xh, const __bf16* xl,
              const __bf16* Wqt_h, const __bf16* Wqt_l, const float* bq,
              __bf16* qhi, __bf16* qlo,
              const __bf16* Wkvt_h, const __bf16* Wkvt_l, const float* bkv,
              __bf16* kvhi, __bf16* kvlo)
{
    __shared__ __attribute__((aligned(16))) char smem[65536];
    const int m0 = blockIdx.y * 128;
    if (blockIdx.x < 2)
        gemm_body<1, 1, 2, 0>(smem, xh, xl, Wkvt_h, Wkvt_l, bkv, kvhi, kvlo,
                              m0, blockIdx.x * 128, 256, 1024);
    else
        gemm_body<1, 1, 2, 1>(smem, xh, xl, Wqt_h, Wqt_l, bq, qhi, qlo,
                              m0, (blockIdx.x - 2) * 128, 1024, 1024);
}

// merged k + v gemm: grid (16, 32) = 512 blocks = 2/CU. Safe merge: v writes
// vtg (overlays xlo) and no branch here reads xlo (q is in the prior dispatch).
__global__ __launch_bounds__(256)
void gemm_kv2(const __bf16* kvhi, const __bf16* kvlo,
              const __bf16* W2th, const __bf16* W2tl, const float* b2,
              __bf16* khi, __bf16* klo,
              const __bf16* Wvt, const float* bv, __bf16* vtg)
{
    __shared__ __attribute__((aligned(16))) char smem[65536];
    const int m0 = blockIdx.y * 128;
    if (blockIdx.x < 8)
        gemm_body<1, 1, 2, 2>(smem, kvhi, kvlo, W2th, W2tl, b2, khi, klo,
                              m0, blockIdx.x * 128, 1024, 256);
    else
        gemm_body<1, 0, 0, 3>(smem, kvhi, kvlo, Wvt, Wvt, bv, vtg, nullptr,
                              m0, (blockIdx.x - 8) * 128, 1024, 256);
}

// o gemm: grid (8, 32) — r3 version restored (r4's 128x64 retile regressed)
__global__ __launch_bounds__(256)
void gemm_o(const __bf16* ybb, const __bf16* Wot, const float* bo, float* out)
{
    __shared__ __attribute__((aligned(16))) char smem[65536];
    gemm_body<0, 0, 1, 0>(smem, ybb, ybb, Wot, Wot, bo, out, nullptr,
                          blockIdx.y * 128, blockIdx.x * 128, 1024, 1024);
}

// ================= flash attention v10: paired-frag single pass ==============
// r6 post-mortem: v9's swizzle killed bank conflicts (8.2M->1.7M) but dur was
// FLAT -> LDS pipe wasn't the wall; the per-step serial chain + barriers are.
// v10: the long tile (31-a) and short tile (a) walk PREFIXES of the same key
// sequence, so process both in ONE pass over keys 0..(31-a)*64:
//  - while the short frag is active (first a+1 steps), both frags' QK^T/PV use
//    the SAME kh/kv/va LDS fragments (K-frag layout is q-tile-independent):
//    one LDS read feeds 2 tiles' MFMAs; the two softmax chains are independent
//    (ILP x2 on the latency chain).
//  - barriers drop 33 -> 32-a (avg 24.5, -26%); K/V staging drops likewise.
//  - per-block wall ~32.7-0.?*a units: mildly unequal, but CU pairs average out.
// Keeps v9's gl2lds + both-sides XOR swizzle (conflicts stay ~1.7M).
// LDS: K/Kl/Vt dbuf 49152 + Pw[4][2] 18432 = 67584 -> 2 blocks/CU.
// r6 counters (v9): dur 70.2, MfmaUtil 20, VALUBusy 40, OCC 18.3, CONF 1.72M.
// Prediction: dur ~55-62, MfmaUtil 24-28, FETCH 22.3->~18 GB, VGPR 130-170.
#define PSP 72
__global__ __launch_bounds__(256, 2)
void attn_v10(const __bf16* __restrict__ qhi, const __bf16* __restrict__ qlo,
              const __bf16* __restrict__ khi, const __bf16* __restrict__ klo,
              const __bf16* __restrict__ vtg, __bf16* __restrict__ yb)
{
    __shared__ __attribute__((aligned(16))) __bf16 Kh2[2][64 * 64];
    __shared__ __attribute__((aligned(16))) __bf16 Kl2[2][64 * 64];
    __shared__ __attribute__((aligned(16))) __bf16 Vt2[2][64 * 64];     // [d][key]
    __shared__ __attribute__((aligned(16))) __bf16 Pw[4][2][16 * PSP];  // [wave][frag][qrow][key]

    const int tid  = threadIdx.x;
    const int w    = tid >> 6;
    const int lane = tid & 63;
    const int l16  = lane & 15;
    const int quad = lane >> 4;

    const int g  = blockIdx.x;
    const int bh = g & 31, a = g >> 5;      // a in 0..15
    const int b  = bh >> 4, h = bh & 15;

    const int q0A = (31 - a) * 64;          // long frag (f=0)
    const int q0B = a * 64;                 // short frag (f=1), keys are a prefix

    const int sr0 = tid >> 3, sc = tid & 7;  // staging: row-within-half, col8
    const int sw  = l16 & 7;                 // read-side swizzle key

    // issue one 64-key step's K(hi,lo)+V into buf via direct gl2lds (6/thread)
    auto stage = [&](int j0, int buf) {
#pragma unroll
        for (int it = 0; it < 2; ++it) {
            int r   = it * 32 + sr0;
            int c8g = sc ^ (r & 7);            // inverse source swizzle
            int d0  = it * 2048 + tid * 8;     // linear dest (lane*16 bytes)
            gl2lds(&khi[(size_t)(b * T_SEQ + j0 + r) * DM + h * HD + c8g * 8], &Kh2[buf][d0]);
            gl2lds(&klo[(size_t)(b * T_SEQ + j0 + r) * DM + h * HD + c8g * 8], &Kl2[buf][d0]);
            gl2lds(&vtg[(size_t)(bh * HD + r) * T_SEQ + j0 + c8g * 8],         &Vt2[buf][d0]);
        }
    };

    // Q B-frags for both tiles (pre-scaled by QSCALE), 2 k-halves each
    bf16x8 qhA[2], qlA[2], qhB[2], qlB[2];
    {
        const size_t offA = (size_t)(b * T_SEQ + q0A + 16 * w + l16) * DM + h * HD;
        const size_t offB = (size_t)(b * T_SEQ + q0B + 16 * w + l16) * DM + h * HD;
#pragma unroll
        for (int s = 0; s < 2; ++s) {
            qhA[s] = *(const bf16x8*)&qhi[offA + s * 32 + quad * 8];
            qlA[s] = *(const bf16x8*)&qlo[offA + s * 32 + quad * 8];
            qhB[s] = *(const bf16x8*)&qhi[offB + s * 32 + quad * 8];
            qlB[s] = *(const bf16x8*)&qlo[offB + s * 32 + quad * 8];
        }
    }

    f32x4 oA[4], oB[4];
#pragma unroll
    for (int i = 0; i < 4; ++i) { oA[i] = (f32x4)0.0f; oB[i] = (f32x4)0.0f; }
    float mA = -1e30f, lA = 0.f, mB = -1e30f, lB = 0.f;

    stage(0, 0);

    // softmax for one frag: mask, row-max (cross-quad shfl), exp2, P-pack, o-rescale
    auto softmax = [&](f32x4* sa, float& m_i, float& l_i, f32x4* o,
                       __bf16* pw, int q0f, int j0) {
        const int  qr   = q0f + 16 * w + l16;
        const bool need = (j0 + 63 > q0f + 16 * w);
        if (need) {
#pragma unroll
            for (int kc = 0; kc < 4; ++kc)
#pragma unroll
                for (int r = 0; r < 4; ++r)
                    if (j0 + kc * 16 + quad * 4 + r > qr) sa[kc][r] = -1e30f;
        }
        float mx = -1e30f;
#pragma unroll
        for (int kc = 0; kc < 4; ++kc)
#pragma unroll
            for (int r = 0; r < 4; ++r) mx = fmaxf(mx, sa[kc][r]);
        mx = fmaxf(mx, __shfl_xor(mx, 16));
        mx = fmaxf(mx, __shfl_xor(mx, 32));
        float mn    = fmaxf(fmaxf(m_i, mx), -1e20f);
        float alpha = exp2f(m_i - mn);
        m_i = mn;
        float rs = 0.f;
#pragma unroll
        for (int kc = 0; kc < 4; ++kc) {
            float p0 = exp2f(sa[kc][0] - mn);
            float p1 = exp2f(sa[kc][1] - mn);
            float p2 = exp2f(sa[kc][2] - mn);
            float p3 = exp2f(sa[kc][3] - mn);
            rs += (p0 + p1) + (p2 + p3);
            bf16x4 pk = { (__bf16)p0, (__bf16)p1, (__bf16)p2, (__bf16)p3 };
            *(bf16x4*)&pw[l16 * PSP + kc * 16 + quad * 4] = pk;
        }
        rs += __shfl_xor(rs, 16);
        rs += __shfl_xor(rs, 32);
        l_i = l_i * alpha + rs;
#pragma unroll
        for (int dc = 0; dc < 4; ++dc) o[dc] *= alpha;
    };

    for (int j0 = 0; j0 <= q0A; j0 += 64) {
        const int  cur  = (j0 >> 6) & 1;
        const bool actB = (j0 <= q0B);     // short frag active on prefix steps
        __syncthreads();                   // drains gl2lds(buf[cur]); buf^1 readers done
        if (j0 + 64 <= q0A) stage(j0 + 64, cur ^ 1);   // overlaps compute

        const __bf16* Kh = Kh2[cur];
        const __bf16* Kl = Kl2[cur];
        const __bf16* Vt = Vt2[cur];

        // S^T = K Q^T for both frags off the SAME kh/kv fragments
        f32x4 saA[4], saB[4];
#pragma unroll
        for (int i = 0; i < 4; ++i) { saA[i] = (f32x4)0.0f; saB[i] = (f32x4)0.0f; }
#pragma unroll
        for (int s = 0; s < 2; ++s) {
            const int c8s = ((s * 4 + quad) ^ sw) * 8;   // swizzled col
#pragma unroll
            for (int kc = 0; kc < 4; ++kc) {
                bf16x8 kh = *(const bf16x8*)&Kh[(kc * 16 + l16) * 64 + c8s];
                bf16x8 kv = *(const bf16x8*)&Kl[(kc * 16 + l16) * 64 + c8s];
                saA[kc] = mfma16(kh, qhA[s], saA[kc]);
                saA[kc] = mfma16(kv, qhA[s], saA[kc]);
                saA[kc] = mfma16(kh, qlA[s], saA[kc]);
                if (actB) {
                    saB[kc] = mfma16(kh, qhB[s], saB[kc]);
                    saB[kc] = mfma16(kv, qhB[s], saB[kc]);
                    saB[kc] = mfma16(kh, qlB[s], saB[kc]);
                }
            }
        }

        // two independent softmax chains (ILP)
        softmax(saA, mA, lA, oA, &Pw[w][0][0], q0A, j0);
        if (actB) softmax(saB, mB, lB, oB, &Pw[w][1][0], q0B, j0);

        // O^T += V^T P^T for both frags off the SAME va fragments
#pragma unroll
        for (int s = 0; s < 2; ++s) {
            const int c8s = ((s * 4 + quad) ^ sw) * 8;
            bf16x8 pbA = *(const bf16x8*)&Pw[w][0][l16 * PSP + s * 32 + quad * 8];
            bf16x8 pbB;
            if (actB) pbB = *(const bf16x8*)&Pw[w][1][l16 * PSP + s * 32 + quad * 8];
#pragma unroll
            for (int dc = 0; dc < 4; ++dc) {
                bf16x8 va = *(const bf16x8*)&Vt[(dc * 16 + l16) * 64 + c8s];
                oA[dc] = mfma16(va, pbA, oA[dc]);
                if (actB) oB[dc] = mfma16(va, pbB, oB[dc]);
            }
        }
    }

    // epilogue x2: normalize, transpose via per-wave P buffer, coalesced store
#pragma unroll
    for (int f = 0; f < 2; ++f) {
        const f32x4* o    = f ? oB : oA;
        const float  invl = 1.0f / (f ? lB : lA);
        const int    q0f  = f ? q0B : q0A;
        __bf16* pw = &Pw[w][f][0];
#pragma unroll
        for (int dc = 0; dc < 4; ++dc) {
            bf16x4 ov = { (__bf16)(o[dc][0] * invl), (__bf16)(o[dc][1] * invl),
                          (__bf16)(o[dc][2] * invl), (__bf16)(o[dc][3] * invl) };
            *(bf16x4*)&pw[l16 * PSP + dc * 16 + quad * 4] = ov;
        }
        const int qrl  = lane >> 2;          // 0..15
        const int dch  = (lane & 3) * 16;    // 0,16,32,48
        const int qrow = q0f + 16 * w + qrl;
        const __bf16* src = &pw[qrl * PSP + dch];
        __bf16*       dst = &yb[(size_t)(b * T_SEQ + qrow) * DM + h * HD + dch];
        *(bf16x8*)dst       = *(const bf16x8*)src;
        *(bf16x8*)(dst + 8) = *(const bf16x8*)(src + 8);
    }
}

extern "C" void kernel_launch(void* const* d_in, const int* in_sizes, int n_in,
                              void* d_out, int out_size, void* d_ws, size_t ws_size,
                              hipStream_t stream)
{
    (void)in_sizes; (void)n_in; (void)out_size; (void)ws_size;

    const float* x   = (const float*)d_in[0];
    const float* Wq  = (const float*)d_in[2];
    const float* bq  = (const float*)d_in[3];
    const float* Wkv = (const float*)d_in[4];
    const float* bkv = (const float*)d_in[5];
    const float* Wk  = (const float*)d_in[6];
    const float* bk  = (const float*)d_in[7];
    const float* Wv  = (const float*)d_in[8];
    const float* bv  = (const float*)d_in[9];
    const float* Wo  = (const float*)d_in[10];
    const float* bo  = (const float*)d_in[11];
    const float* Wkr = (const float*)d_in[12];

    const int    BT = 2 * T_SEQ;   // 4096
    const size_t MB = 1024 * 1024;
    char* base = (char*)d_ws;

    __bf16* xhi    = (__bf16*)(base +  0 * MB);
    __bf16* xlo    = (__bf16*)(base +  8 * MB);
    __bf16* qhi    = (__bf16*)(base + 16 * MB);
    __bf16* qlo    = (__bf16*)(base + 24 * MB);
    __bf16* Wqt_h  = (__bf16*)(base + 32 * MB);
    __bf16* Wqt_l  = (__bf16*)(base + 34 * MB);
    __bf16* Wkvt_h = (__bf16*)(base + 36 * MB);
    __bf16* Wkvt_l = (__bf16*)(base + 37 * MB);
    __bf16* kvhi   = (__bf16*)(base + 38 * MB);
    __bf16* kvlo   = (__bf16*)(base + 40 * MB);
    __bf16* W2t_h  = (__bf16*)(base + 42 * MB);
    __bf16* W2t_l  = (__bf16*)(base + 42 * MB + 512 * 1024);
    __bf16* Wvt    = (__bf16*)(base + 43 * MB);
    __bf16* Wot    = (__bf16*)(base + 43 * MB + 512 * 1024);
    float*  b2     = (float*) (base + 45 * MB + 512 * 1024);
    __bf16* vtg    = (__bf16*)(base +  8 * MB);               // overlays xlo (dead after gemm_qkv)
    __bf16* ybb    = (__bf16*)(base +  0 * MB);               // overlays xhi (dead after gemm_qkv)
    __bf16* khi    = (__bf16*)d_out;                          // d_out as scratch
    __bf16* klo    = (__bf16*)d_out + (size_t)BT * DM;        // overwritten by o gemm

    dim3 blk(256);
    prep<<<3716, blk, 0, stream>>>(x, Wq, Wkv, Wv, Wo, Wk, Wkr, bk,
                                   xhi, xlo, Wqt_h, Wqt_l, Wkvt_h, Wkvt_l,
                                   Wvt, Wot, W2t_h, W2t_l, b2);
    gemm_qkv<<<dim3(10, 32), blk, 0, stream>>>(xhi, xlo, Wqt_h, Wqt_l, bq, qhi, qlo,
                                               Wkvt_h, Wkvt_l, bkv, kvhi, kvlo);
    gemm_kv2<<<dim3(16, 32), blk, 0, stream>>>(kvhi, kvlo, W2t_h, W2t_l, b2,
                                               khi, klo, Wvt, bv, vtg);
    attn_v10<<<512, blk, 0, stream>>>(qhi, qlo, khi, klo, vtg, ybb);
    gemm_o<<<dim3(8, 32), blk, 0, stream>>>(ybb, Wot, bo, (float*)d_out);
}

// Round 13
// 260.943 us; speedup vs baseline: 1.0403x; 1.0403x over previous
//
#include <hip/hip_runtime.h>
#include <hip/hip_bf16.h>
#include <math.h>

typedef __bf16 bf16x8 __attribute__((ext_vector_type(8)));
typedef __bf16 bf16x4 __attribute__((ext_vector_type(4)));
typedef float  f32x4  __attribute__((ext_vector_type(4)));

#define T_SEQ 2048
#define NH    16
#define HD    64
#define DM    1024
// softmax logits pre-scaled by 1/sqrt(64) * log2(e) so we can use exp2
#define QSCALE 0.18033688011112043f

__device__ __forceinline__ f32x4 mfma16(bf16x8 a, bf16x8 b, f32x4 c) {
    return __builtin_amdgcn_mfma_f32_16x16x32_bf16(a, b, c, 0, 0, 0);
}

// async global->LDS, 16B per lane. LDS dest is wave-uniform base + lane*16
// (our staging layout is exactly that). Barrier's implicit vmcnt(0) drains.
__device__ __forceinline__ void gl2lds(const void* g, void* l) {
    __builtin_amdgcn_global_load_lds(
        (const __attribute__((address_space(1))) void*)g,
        (__attribute__((address_space(3))) void*)l, 16, 0, 0);
}

// ================= prep (one dispatch) =================
__device__ __forceinline__ void tsplit_body(const float* __restrict__ in,
                                            __bf16* __restrict__ oh, __bf16* __restrict__ ol,
                                            int K, int N, int n0, int k0, int SPLIT,
                                            float* tile /* [64][65] LDS */)
{
    const int tid = threadIdx.x;
#pragma unroll
    for (int it = 0; it < 2; ++it) {
        int r = it * 32 + (tid >> 3), c8 = (tid & 7) * 8;
        f32x4 a0 = *(const f32x4*)&in[(size_t)(k0 + r) * N + n0 + c8];
        f32x4 a1 = *(const f32x4*)&in[(size_t)(k0 + r) * N + n0 + c8 + 4];
#pragma unroll
        for (int j = 0; j < 4; ++j) { tile[r * 65 + c8 + j] = a0[j]; tile[r * 65 + c8 + 4 + j] = a1[j]; }
    }
    __syncthreads();
    const int n = tid >> 2, kb = (tid & 3) * 16;
    bf16x8 h0, h1, l0, l1;
#pragma unroll
    for (int j = 0; j < 8; ++j) {
        float v0 = tile[(kb + j) * 65 + n], v1 = tile[(kb + 8 + j) * 65 + n];
        __bf16 hb0 = (__bf16)v0, hb1 = (__bf16)v1;
        h0[j] = hb0; h1[j] = hb1;
        if (SPLIT) { l0[j] = (__bf16)(v0 - (float)hb0); l1[j] = (__bf16)(v1 - (float)hb1); }
    }
    size_t o = (size_t)(n0 + n) * K + k0 + kb;
    *(bf16x8*)&oh[o] = h0; *(bf16x8*)&oh[o + 8] = h1;
    if (SPLIT) { *(bf16x8*)&ol[o] = l0; *(bf16x8*)&ol[o + 8] = l1; }
}

__global__ __launch_bounds__(256)
void prep(const float* __restrict__ x, const float* __restrict__ Wq,
          const float* __restrict__ Wkv, const float* __restrict__ Wv,
          const float* __restrict__ Wo, const float* __restrict__ Wk,
          const float* __restrict__ Wkr, const float* __restrict__ bk,
          __bf16* xh, __bf16* xl, __bf16* Wqt_h, __bf16* Wqt_l,
          __bf16* Wkvt_h, __bf16* Wkvt_l, __bf16* Wvt, __bf16* Wot,
          __bf16* W2th, __bf16* W2tl, float* b2)
{
    __shared__ float tile[64 * 65];
    const int g = blockIdx.x, tid = threadIdx.x;
    if (g < 2048) {                       // split x -> xh/xl
        size_t idx = ((size_t)g * 256 + tid) * 8;
        f32x4 a0 = *(const f32x4*)&x[idx];
        f32x4 a1 = *(const f32x4*)&x[idx + 4];
        bf16x8 h, l;
#pragma unroll
        for (int j = 0; j < 4; ++j) {
            __bf16 h0 = (__bf16)a0[j];
            h[j]     = h0; l[j]     = (__bf16)(a0[j] - (float)h0);
            __bf16 h1 = (__bf16)a1[j];
            h[4 + j] = h1; l[4 + j] = (__bf16)(a1[j] - (float)h1);
        }
        *(bf16x8*)&xh[idx] = h;
        *(bf16x8*)&xl[idx] = l;
    } else if (g < 2304) {                // Wq -> [N,K] split
        int i = g - 2048;
        tsplit_body(Wq, Wqt_h, Wqt_l, 1024, 1024, (i & 15) * 64, (i >> 4) * 64, 1, tile);
    } else if (g < 2368) {                // Wkv -> split
        int i = g - 2304;
        tsplit_body(Wkv, Wkvt_h, Wkvt_l, 1024, 256, (i & 3) * 64, (i >> 2) * 64, 1, tile);
    } else if (g < 2432) {                // Wv -> trunc
        int i = g - 2368;
        tsplit_body(Wv, Wvt, nullptr, 256, 1024, (i & 15) * 64, (i >> 4) * 64, 0, tile);
    } else if (g < 2688) {                // Wo -> trunc
        int i = g - 2432;
        tsplit_body(Wo, Wot, nullptr, 1024, 1024, (i & 15) * 64, (i >> 4) * 64, 0, tile);
    } else {                              // W2 = Wk_h @ Wkr (transposed split) + b2
        int o    = (g - 2688) * 256 + tid;
        int rowk = o >> 10, col = o & 1023;
        int h = col >> 6, d = col & 63;
        float acc = 0.0f;
        if (rowk < 256) {
#pragma unroll 8
            for (int j = 0; j < 64; ++j)
                acc += Wk[(size_t)rowk * DM + h * HD + j] * Wkr[j * HD + d];
            __bf16 hb = (__bf16)acc;
            W2th[(size_t)col * 256 + rowk] = hb;
            W2tl[(size_t)col * 256 + rowk] = (__bf16)(acc - (float)hb);
        } else {
#pragma unroll 8
            for (int j = 0; j < 64; ++j)
                acc += bk[h * HD + j] * Wkr[j * HD + d];
            b2[col] = acc;
        }
    }
}

// ================= 128x128-tile GEMM, async-pipelined K-loop =================
// A bf16 [M,K] (hi + optional lo), B bf16 [N,K] (hi + optional lo)
// OUTM: 0 bf16 | 1 fp32 | 2 dual split bf16
// EPI:  0 bias | 1 RoPE*QSCALE split-out | 2 bias then *t | 3 v->vtg transpose
// K-loop: DOUBLE-BUFFERED gl2lds panels, ONE barrier per 32-K step:
//   barrier; issue gl2lds(step j+1 -> buf^1); compute(buf)
// LDS layout per buf (32768 B): Ah @0, Al @8192, Bh @16384, Bl @24576.
// NOTE: never pass nullptr for a lo pointer with DUAL*=1 (r5-r7 bug).
// NOTE: branches of ONE dispatch must never write memory another branch reads
// (r9 bug: v wrote vtg overlaying xlo read by q). q+kv / k+v merges are safe.
// NOTE r4: 128x64 retile of gemm_o REGRESSED (+9 µs): fewer MFMA per LDS
// B-read + 2x barriers + cross-block LDS bank contention beat the occupancy
// gain. Keep fat 128x128 tiles even at 1 block/CU.
template <int DUALA, int DUALB, int OUTM, int EPI>
__device__ __forceinline__
void gemm_body(char* smem,
               const __bf16* __restrict__ Ahi, const __bf16* __restrict__ Alo,
               const __bf16* __restrict__ Bhi, const __bf16* __restrict__ Blo,
               const float* __restrict__ bias, void* __restrict__ Cp,
               void* __restrict__ Cp2, int m0, int n0, int N, int K)
{
    const int tid  = threadIdx.x;
    const int w    = tid >> 6;
    const int lane = tid & 63;
    const int l16  = lane & 15;
    const int quad = lane >> 4;
    const int wy   = w >> 1, wx = w & 1;

    f32x4 acc[4][4];
#pragma unroll
    for (int i = 0; i < 4; ++i)
#pragma unroll
        for (int j = 0; j < 4; ++j) acc[i][j] = (f32x4)0.0f;

    auto stage = [&](int k0, int buf) {
        char* bb = smem + buf * 32768;
#pragma unroll
        for (int i = 0; i < 2; ++i) {
            int s = i * 256 + tid, row = s >> 2, c8 = (s & 3) * 8;
            size_t aoff = (size_t)(m0 + row) * K + k0 + c8;
            size_t boff = (size_t)(n0 + row) * K + k0 + c8;
            char*  dst  = bb + (row * 32 + c8) * 2;
            gl2lds(&Ahi[aoff], dst);
            if (DUALA) gl2lds(&Alo[aoff], dst + 8192);
            gl2lds(&Bhi[boff], dst + 16384);
            if (DUALB) gl2lds(&Blo[boff], dst + 24576);
        }
    };

    stage(0, 0);
    const int J = K >> 5;
    for (int j = 0; j < J; ++j) {
        __syncthreads();               // drains gl2lds for step j (all waves)
        if (j + 1 < J) stage((j + 1) << 5, (j + 1) & 1);   // overlaps compute

        const __bf16* Ah = (const __bf16*)(smem + (j & 1) * 32768);
        const __bf16* Al = Ah + 4096;
        const __bf16* Bh = Ah + 8192;
        const __bf16* Bl = Ah + 12288;

        bf16x8 bfh[4], bfl[4];
#pragma unroll
        for (int ct = 0; ct < 4; ++ct) {
            bfh[ct] = *(const bf16x8*)&Bh[(wx * 64 + ct * 16 + l16) * 32 + quad * 8];
            if (DUALB) bfl[ct] = *(const bf16x8*)&Bl[(wx * 64 + ct * 16 + l16) * 32 + quad * 8];
        }
#pragma unroll
        for (int mf = 0; mf < 4; ++mf) {
            bf16x8 ah = *(const bf16x8*)&Ah[(wy * 64 + mf * 16 + l16) * 32 + quad * 8];
            bf16x8 al;
            if (DUALA) al = *(const bf16x8*)&Al[(wy * 64 + mf * 16 + l16) * 32 + quad * 8];
#pragma unroll
            for (int ct = 0; ct < 4; ++ct) {
                acc[mf][ct] = mfma16(ah, bfh[ct], acc[mf][ct]);
                if (DUALA) acc[mf][ct] = mfma16(al, bfh[ct], acc[mf][ct]);
                if (DUALB) acc[mf][ct] = mfma16(ah, bfl[ct], acc[mf][ct]);
            }
        }
    }

    float bias_v[4];
#pragma unroll
    for (int ct = 0; ct < 4; ++ct)
        bias_v[ct] = bias ? bias[n0 + wx * 64 + ct * 16 + l16] : 0.0f;

    if (EPI == 1) {  // RoPE (q): pair (d, d+32) = (ct, ct+2); *QSCALE; split out
        __bf16* Chi = (__bf16*)Cp;
        __bf16* Clo = (__bf16*)Cp2;
#pragma unroll
        for (int mf = 0; mf < 4; ++mf) {
#pragma unroll
            for (int r = 0; r < 4; ++r) {
                int   m = m0 + wy * 64 + mf * 16 + quad * 4 + r;
                float t = (float)(m & (T_SEQ - 1));
#pragma unroll
                for (int ct = 0; ct < 2; ++ct) {
                    int   d   = ct * 16 + l16;
                    float inv = powf(10000.0f, -(float)d * (1.0f / 32.0f));
                    float sv, cv;
                    sincosf(t * inv, &sv, &cv);
                    float lo = acc[mf][ct][r]     + bias_v[ct];
                    float hi = acc[mf][ct + 2][r] + bias_v[ct + 2];
                    float v0 = (lo * cv - hi * sv) * QSCALE;
                    float v1 = (hi * cv + lo * sv) * QSCALE;
                    size_t i0 = (size_t)m * N + n0 + wx * 64 + d;
                    size_t i1 = i0 + 32;
                    __bf16 h0 = (__bf16)v0, h1 = (__bf16)v1;
                    Chi[i0] = h0; Clo[i0] = (__bf16)(v0 - (float)h0);
                    Chi[i1] = h1; Clo[i1] = (__bf16)(v1 - (float)h1);
                }
            }
        }
    } else if (EPI == 3) {  // v: write vtg[bh][d][t] via per-wave LDS transpose
        __syncthreads();
        __bf16* vt = (__bf16*)(smem + w * 9216);   // [64][72]
#pragma unroll
        for (int mf = 0; mf < 4; ++mf)
#pragma unroll
            for (int ct = 0; ct < 4; ++ct)
#pragma unroll
                for (int r = 0; r < 4; ++r)
                    vt[(ct * 16 + l16) * 72 + mf * 16 + quad * 4 + r] =
                        (__bf16)(acc[mf][ct][r] + bias_v[ct]);
        const int bb   = m0 >> 11;
        const int head = (n0 + wx * 64) >> 6;
        const int bh   = bb * 16 + head;
        __bf16* out    = (__bf16*)Cp;
        size_t  gbase  = ((size_t)(bh * 64 + lane)) * T_SEQ + (m0 & (T_SEQ - 1)) + wy * 64;
#pragma unroll
        for (int j8 = 0; j8 < 8; ++j8)
            *(bf16x8*)&out[gbase + j8 * 8] = *(const bf16x8*)&vt[lane * 72 + j8 * 8];
    } else {
#pragma unroll
        for (int mf = 0; mf < 4; ++mf) {
#pragma unroll
            for (int r = 0; r < 4; ++r) {
                int   m     = m0 + wy * 64 + mf * 16 + quad * 4 + r;
                float scale = (EPI == 2) ? (float)(m & (T_SEQ - 1)) : 1.0f;
#pragma unroll
                for (int ct = 0; ct < 4; ++ct) {
                    float  v   = (acc[mf][ct][r] + bias_v[ct]) * scale;
                    size_t idx = (size_t)m * N + n0 + wx * 64 + ct * 16 + l16;
                    if (OUTM == 1)      ((float*)Cp)[idx]  = v;
                    else if (OUTM == 0) ((__bf16*)Cp)[idx] = (__bf16)v;
                    else {
                        __bf16 hb = (__bf16)v;
                        ((__bf16*)Cp)[idx]  = hb;
                        ((__bf16*)Cp2)[idx] = (__bf16)(v - (float)hb);
                    }
                }
            }
        }
    }
}

// merged kv + q gemm: grid (10, 32) = 320 blocks (kv first so it fills early)
__global__ __launch_bounds__(256)
void gemm_qkv(const __bf16* xh, const __bf16* xl,
              const __bf16* Wqt_h, const __bf16* Wqt_l, const float* bq,
              __bf16* qhi, __bf16* qlo,
              const __bf16* Wkvt_h, const __bf16* Wkvt_l, const float* bkv,
              __bf16* kvhi, __bf16* kvlo)
{
    __shared__ __attribute__((aligned(16))) char smem[65536];
    const int m0 = blockIdx.y * 128;
    if (blockIdx.x < 2)
        gemm_body<1, 1, 2, 0>(smem, xh, xl, Wkvt_h, Wkvt_l, bkv, kvhi, kvlo,
                              m0, blockIdx.x * 128, 256, 1024);
    else
        gemm_body<1, 1, 2, 1>(smem, xh, xl, Wqt_h, Wqt_l, bq, qhi, qlo,
                              m0, (blockIdx.x - 2) * 128, 1024, 1024);
}

// merged k + v gemm: grid (16, 32) = 512 blocks = 2/CU. Safe merge: v writes
// vtg (overlays xlo) and no branch here reads xlo (q is in the prior dispatch).
__global__ __launch_bounds__(256)
void gemm_kv2(const __bf16* kvhi, const __bf16* kvlo,
              const __bf16* W2th, const __bf16* W2tl, const float* b2,
              __bf16* khi, __bf16* klo,
              const __bf16* Wvt, const float* bv, __bf16* vtg)
{
    __shared__ __attribute__((aligned(16))) char smem[65536];
    const int m0 = blockIdx.y * 128;
    if (blockIdx.x < 8)
        gemm_body<1, 1, 2, 2>(smem, kvhi, kvlo, W2th, W2tl, b2, khi, klo,
                              m0, blockIdx.x * 128, 1024, 256);
    else
        gemm_body<1, 0, 0, 3>(smem, kvhi, kvlo, Wvt, Wvt, bv, vtg, nullptr,
                              m0, (blockIdx.x - 8) * 128, 1024, 256);
}

// o gemm: grid (8, 32) — r3 version restored (r4's 128x64 retile regressed)
__global__ __launch_bounds__(256)
void gemm_o(const __bf16* ybb, const __bf16* Wot, const float* bo, float* out)
{
    __shared__ __attribute__((aligned(16))) char smem[65536];
    gemm_body<0, 0, 1, 0>(smem, ybb, ybb, Wot, Wot, bo, out, nullptr,
                          blockIdx.y * 128, blockIdx.x * 128, 1024, 1024);
}

// ================= flash attention v9 (REVERTED from v10) + max-tree =========
// r12 post-mortem: v10's paired-frag single pass REGRESSED 70.2 -> 77.7 µs
// (MfmaUtil 20->18, VALUBusy 40->46.5): the two softmax chains serialize at
// issue — in-wave ILP does NOT shorten the softmax critical chain; per-step
// cost scales ~linearly with frag count, so 33 cheap steps beat 24.5 costly
// ones. REVERTED to v9 (verified 70.2 µs attn / 257.7 total).
// One exact-arithmetic tweak rides along: row-max as a depth-4 pairwise
// fmax TREE (was a 15-deep serial chain; clang can fuse to v_max3; max is
// associative-exact so absmax is bit-identical).
// v9 recap: equal-length blocks (64-row tiles, (31-a)+(a) serial phases,
// 33 steps each), gl2lds K/V staging + both-sides XOR swizzle (conflicts
// 1.72M), LDS 58368 -> 2 blocks/CU.
// r6 counters (v9): dur 70.2, MfmaUtil 20, VALUBusy 40, OCC 18.3, CONF 1.72M.
// Prediction: dur 69-70.5 (tree worth 0-1.5 µs), absmax 0.00390625 exact.
#define PSP 72
__global__ __launch_bounds__(256, 2)
void attn_v9(const __bf16* __restrict__ qhi, const __bf16* __restrict__ qlo,
             const __bf16* __restrict__ khi, const __bf16* __restrict__ klo,
             const __bf16* __restrict__ vtg, __bf16* __restrict__ yb)
{
    __shared__ __attribute__((aligned(16))) __bf16 Kh2[2][64 * 64];
    __shared__ __attribute__((aligned(16))) __bf16 Kl2[2][64 * 64];
    __shared__ __attribute__((aligned(16))) __bf16 Vt2[2][64 * 64];   // [d][key]
    __shared__ __attribute__((aligned(16))) __bf16 Pw[4][16 * PSP];   // [wave][qrow][key]

    const int tid  = threadIdx.x;
    const int w    = tid >> 6;
    const int lane = tid & 63;
    const int l16  = lane & 15;
    const int quad = lane >> 4;

    const int g  = blockIdx.x;
    const int bh = g & 31, a = g >> 5;      // a in 0..15; same-bh blocks share an XCD
    const int b  = bh >> 4, h = bh & 15;

    const int sr0 = tid >> 3, sc = tid & 7;  // staging: row-within-half, col8
    const int sw  = l16 & 7;                 // read-side swizzle key

    // issue one 64-key step's K(hi,lo)+V into buf via direct gl2lds (6/thread)
    auto stage = [&](int j0, int buf) {
#pragma unroll
        for (int it = 0; it < 2; ++it) {
            int r   = it * 32 + sr0;
            int c8g = sc ^ (r & 7);            // inverse source swizzle
            int d0  = it * 2048 + tid * 8;     // linear dest (lane*16 bytes)
            gl2lds(&khi[(size_t)(b * T_SEQ + j0 + r) * DM + h * HD + c8g * 8], &Kh2[buf][d0]);
            gl2lds(&klo[(size_t)(b * T_SEQ + j0 + r) * DM + h * HD + c8g * 8], &Kl2[buf][d0]);
            gl2lds(&vtg[(size_t)(bh * HD + r) * T_SEQ + j0 + c8g * 8],         &Vt2[buf][d0]);
        }
    };

    for (int ph = 0; ph < 2; ++ph) {
        const int u  = ph ? a : (31 - a);   // long tile first, then short
        const int q0 = u * 64;

        // Q B-frag for this 64-row tile (pre-scaled by QSCALE), 2 k-halves
        bf16x8 qh[2], ql[2];
        {
            const int    qr   = q0 + 16 * w + l16;
            const size_t qoff = (size_t)(b * T_SEQ + qr) * DM + h * HD;
#pragma unroll
            for (int s = 0; s < 2; ++s) {
                qh[s] = *(const bf16x8*)&qhi[qoff + s * 32 + quad * 8];
                ql[s] = *(const bf16x8*)&qlo[qoff + s * 32 + quad * 8];
            }
        }

        f32x4 o[4];
#pragma unroll
        for (int i = 0; i < 4; ++i) o[i] = (f32x4)0.0f;
        float m_i = -1e30f, l_i = 0.f;

        __syncthreads();   // all waves done reading LDS from previous phase
        stage(0, 0);

        for (int j0 = 0; j0 <= q0; j0 += 64) {
            const int  cur = (j0 >> 6) & 1;
            __syncthreads();            // drains gl2lds(buf[cur]); buf[cur^1] readers done
            if (j0 + 64 <= q0) stage(j0 + 64, cur ^ 1);   // overlaps compute

            const __bf16* Kh = Kh2[cur];
            const __bf16* Kl = Kl2[cur];
            const __bf16* Vt = Vt2[cur];

            // S^T = K Q^T: rows=keys (kc,quad,reg), cols=qrows (l16)
            f32x4 sa[4];
#pragma unroll
            for (int i = 0; i < 4; ++i) sa[i] = (f32x4)0.0f;
#pragma unroll
            for (int s = 0; s < 2; ++s) {
                const int c8s = ((s * 4 + quad) ^ sw) * 8;   // swizzled col
#pragma unroll
                for (int kc = 0; kc < 4; ++kc) {
                    bf16x8 kh = *(const bf16x8*)&Kh[(kc * 16 + l16) * 64 + c8s];
                    bf16x8 kv = *(const bf16x8*)&Kl[(kc * 16 + l16) * 64 + c8s];
                    sa[kc] = mfma16(kh, qh[s], sa[kc]);
                    sa[kc] = mfma16(kv, qh[s], sa[kc]);
                    sa[kc] = mfma16(kh, ql[s], sa[kc]);
                }
            }

            // causal mask + online softmax (cross-quad shfl reductions)
            const int  qr   = q0 + 16 * w + l16;
            const bool need = (j0 + 63 > q0 + 16 * w);
            if (need) {
#pragma unroll
                for (int kc = 0; kc < 4; ++kc)
#pragma unroll
                    for (int r = 0; r < 4; ++r)
                        if (j0 + kc * 16 + quad * 4 + r > qr) sa[kc][r] = -1e30f;
            }
            // depth-4 pairwise max tree (exact; was 15-deep serial chain)
            float t0 = fmaxf(fmaxf(sa[0][0], sa[0][1]), fmaxf(sa[0][2], sa[0][3]));
            float t1 = fmaxf(fmaxf(sa[1][0], sa[1][1]), fmaxf(sa[1][2], sa[1][3]));
            float t2 = fmaxf(fmaxf(sa[2][0], sa[2][1]), fmaxf(sa[2][2], sa[2][3]));
            float t3 = fmaxf(fmaxf(sa[3][0], sa[3][1]), fmaxf(sa[3][2], sa[3][3]));
            float mx = fmaxf(fmaxf(t0, t1), fmaxf(t2, t3));
            mx = fmaxf(mx, __shfl_xor(mx, 16));
            mx = fmaxf(mx, __shfl_xor(mx, 32));
            float mn    = fmaxf(fmaxf(m_i, mx), -1e20f);
            float alpha = exp2f(m_i - mn);
            m_i = mn;
            float rs = 0.f;
            __bf16* pw = &Pw[w][0];
#pragma unroll
            for (int kc = 0; kc < 4; ++kc) {
                float p0 = exp2f(sa[kc][0] - mn);
                float p1 = exp2f(sa[kc][1] - mn);
                float p2 = exp2f(sa[kc][2] - mn);
                float p3 = exp2f(sa[kc][3] - mn);
                rs += (p0 + p1) + (p2 + p3);
                bf16x4 pk = { (__bf16)p0, (__bf16)p1, (__bf16)p2, (__bf16)p3 };
                *(bf16x4*)&pw[l16 * PSP + kc * 16 + quad * 4] = pk;
            }
            rs += __shfl_xor(rs, 16);
            rs += __shfl_xor(rs, 32);
            l_i = l_i * alpha + rs;
#pragma unroll
            for (int dc = 0; dc < 4; ++dc) o[dc] *= alpha;

            // O^T += V^T P^T: rows=d (dc,quad,reg), cols=qrows (l16)
#pragma unroll
            for (int s = 0; s < 2; ++s) {
                const int c8s = ((s * 4 + quad) ^ sw) * 8;
                bf16x8 pb = *(const bf16x8*)&pw[l16 * PSP + s * 32 + quad * 8];
#pragma unroll
                for (int dc = 0; dc < 4; ++dc) {
                    bf16x8 va = *(const bf16x8*)&Vt[(dc * 16 + l16) * 64 + c8s];
                    o[dc] = mfma16(va, pb, o[dc]);
                }
            }
        }

        // epilogue: normalize, transpose via per-wave P buffer, coalesced store
        {
            float   invl = 1.0f / l_i;
            __bf16* pw   = &Pw[w][0];
#pragma unroll
            for (int dc = 0; dc < 4; ++dc) {
                bf16x4 ov = { (__bf16)(o[dc][0] * invl), (__bf16)(o[dc][1] * invl),
                              (__bf16)(o[dc][2] * invl), (__bf16)(o[dc][3] * invl) };
                *(bf16x4*)&pw[l16 * PSP + dc * 16 + quad * 4] = ov;
            }
            const int qrl  = lane >> 2;          // 0..15
            const int dch  = (lane & 3) * 16;    // 0,16,32,48
            const int qrow = q0 + 16 * w + qrl;
            const __bf16* src = &pw[qrl * PSP + dch];
            __bf16*       dst = &yb[(size_t)(b * T_SEQ + qrow) * DM + h * HD + dch];
            *(bf16x8*)dst       = *(const bf16x8*)src;
            *(bf16x8*)(dst + 8) = *(const bf16x8*)(src + 8);
        }
    }
}

extern "C" void kernel_launch(void* const* d_in, const int* in_sizes, int n_in,
                              void* d_out, int out_size, void* d_ws, size_t ws_size,
                              hipStream_t stream)
{
    (void)in_sizes; (void)n_in; (void)out_size; (void)ws_size;

    const float* x   = (const float*)d_in[0];
    const float* Wq  = (const float*)d_in[2];
    const float* bq  = (const float*)d_in[3];
    const float* Wkv = (const float*)d_in[4];
    const float* bkv = (const float*)d_in[5];
    const float* Wk  = (const float*)d_in[6];
    const float* bk  = (const float*)d_in[7];
    const float* Wv  = (const float*)d_in[8];
    const float* bv  = (const float*)d_in[9];
    const float* Wo  = (const float*)d_in[10];
    const float* bo  = (const float*)d_in[11];
    const float* Wkr = (const float*)d_in[12];

    const int    BT = 2 * T_SEQ;   // 4096
    const size_t MB = 1024 * 1024;
    char* base = (char*)d_ws;

    __bf16* xhi    = (__bf16*)(base +  0 * MB);
    __bf16* xlo    = (__bf16*)(base +  8 * MB);
    __bf16* qhi    = (__bf16*)(base + 16 * MB);
    __bf16* qlo    = (__bf16*)(base + 24 * MB);
    __bf16* Wqt_h  = (__bf16*)(base + 32 * MB);
    __bf16* Wqt_l  = (__bf16*)(base + 34 * MB);
    __bf16* Wkvt_h = (__bf16*)(base + 36 * MB);
    __bf16* Wkvt_l = (__bf16*)(base + 37 * MB);
    __bf16* kvhi   = (__bf16*)(base + 38 * MB);
    __bf16* kvlo   = (__bf16*)(base + 40 * MB);
    __bf16* W2t_h  = (__bf16*)(base + 42 * MB);
    __bf16* W2t_l  = (__bf16*)(base + 42 * MB + 512 * 1024);
    __bf16* Wvt    = (__bf16*)(base + 43 * MB);
    __bf16* Wot    = (__bf16*)(base + 43 * MB + 512 * 1024);
    float*  b2     = (float*) (base + 45 * MB + 512 * 1024);
    __bf16* vtg    = (__bf16*)(base +  8 * MB);               // overlays xlo (dead after gemm_qkv)
    __bf16* ybb    = (__bf16*)(base +  0 * MB);               // overlays xhi (dead after gemm_qkv)
    __bf16* khi    = (__bf16*)d_out;                          // d_out as scratch
    __bf16* klo    = (__bf16*)d_out + (size_t)BT * DM;        // overwritten by o gemm

    dim3 blk(256);
    prep<<<3716, blk, 0, stream>>>(x, Wq, Wkv, Wv, Wo, Wk, Wkr, bk,
                                   xhi, xlo, Wqt_h, Wqt_l, Wkvt_h, Wkvt_l,
                                   Wvt, Wot, W2t_h, W2t_l, b2);
    gemm_qkv<<<dim3(10, 32), blk, 0, stream>>>(xhi, xlo, Wqt_h, Wqt_l, bq, qhi, qlo,
                                               Wkvt_h, Wkvt_l, bkv, kvhi, kvlo);
    gemm_kv2<<<dim3(16, 32), blk, 0, stream>>>(kvhi, kvlo, W2t_h, W2t_l, b2,
                                               khi, klo, Wvt, bv, vtg);
    attn_v9<<<512, blk, 0, stream>>>(qhi, qlo, khi, klo, vtg, ybb);
    gemm_o<<<dim3(8, 32), blk, 0, stream>>>(ybb, Wot, bo, (float*)d_out);
}

// Round 19
// 256.237 us; speedup vs baseline: 1.0594x; 1.0184x over previous
//
#include <hip/hip_runtime.h>
#include <hip/hip_bf16.h>
#include <math.h>

typedef __bf16 bf16x8 __attribute__((ext_vector_type(8)));
typedef __bf16 bf16x4 __attribute__((ext_vector_type(4)));
typedef float  f32x4  __attribute__((ext_vector_type(4)));

#define T_SEQ 2048
#define NH    16
#define HD    64
#define DM    1024
// softmax logits pre-scaled by 1/sqrt(64) * log2(e) so we can use exp2
#define QSCALE 0.18033688011112043f

__device__ __forceinline__ f32x4 mfma16(bf16x8 a, bf16x8 b, f32x4 c) {
    return __builtin_amdgcn_mfma_f32_16x16x32_bf16(a, b, c, 0, 0, 0);
}

// async global->LDS, 16B per lane. LDS dest is wave-uniform base + lane*16
// (our staging layout is exactly that). Barrier's implicit vmcnt(0) drains.
__device__ __forceinline__ void gl2lds(const void* g, void* l) {
    __builtin_amdgcn_global_load_lds(
        (const __attribute__((address_space(1))) void*)g,
        (__attribute__((address_space(3))) void*)l, 16, 0, 0);
}

// ================= prep (one dispatch) =================
__device__ __forceinline__ void tsplit_body(const float* __restrict__ in,
                                            __bf16* __restrict__ oh, __bf16* __restrict__ ol,
                                            int K, int N, int n0, int k0, int SPLIT,
                                            float* tile /* [64][65] LDS */)
{
    const int tid = threadIdx.x;
#pragma unroll
    for (int it = 0; it < 2; ++it) {
        int r = it * 32 + (tid >> 3), c8 = (tid & 7) * 8;
        f32x4 a0 = *(const f32x4*)&in[(size_t)(k0 + r) * N + n0 + c8];
        f32x4 a1 = *(const f32x4*)&in[(size_t)(k0 + r) * N + n0 + c8 + 4];
#pragma unroll
        for (int j = 0; j < 4; ++j) { tile[r * 65 + c8 + j] = a0[j]; tile[r * 65 + c8 + 4 + j] = a1[j]; }
    }
    __syncthreads();
    const int n = tid >> 2, kb = (tid & 3) * 16;
    bf16x8 h0, h1, l0, l1;
#pragma unroll
    for (int j = 0; j < 8; ++j) {
        float v0 = tile[(kb + j) * 65 + n], v1 = tile[(kb + 8 + j) * 65 + n];
        __bf16 hb0 = (__bf16)v0, hb1 = (__bf16)v1;
        h0[j] = hb0; h1[j] = hb1;
        if (SPLIT) { l0[j] = (__bf16)(v0 - (float)hb0); l1[j] = (__bf16)(v1 - (float)hb1); }
    }
    size_t o = (size_t)(n0 + n) * K + k0 + kb;
    *(bf16x8*)&oh[o] = h0; *(bf16x8*)&oh[o + 8] = h1;
    if (SPLIT) { *(bf16x8*)&ol[o] = l0; *(bf16x8*)&ol[o + 8] = l1; }
}

__global__ __launch_bounds__(256)
void prep(const float* __restrict__ x, const float* __restrict__ Wq,
          const float* __restrict__ Wkv, const float* __restrict__ Wv,
          const float* __restrict__ Wo, const float* __restrict__ Wk,
          const float* __restrict__ Wkr, const float* __restrict__ bk,
          __bf16* xh, __bf16* xl, __bf16* Wqt_h, __bf16* Wqt_l,
          __bf16* Wkvt_h, __bf16* Wkvt_l, __bf16* Wvt, __bf16* Wot,
          __bf16* W2th, __bf16* W2tl, float* b2, float2* rtab)
{
    __shared__ float tile[64 * 65];
    const int g = blockIdx.x, tid = threadIdx.x;
    if (g < 2048) {                       // split x -> xh/xl
        size_t idx = ((size_t)g * 256 + tid) * 8;
        f32x4 a0 = *(const f32x4*)&x[idx];
        f32x4 a1 = *(const f32x4*)&x[idx + 4];
        bf16x8 h, l;
#pragma unroll
        for (int j = 0; j < 4; ++j) {
            __bf16 h0 = (__bf16)a0[j];
            h[j]     = h0; l[j]     = (__bf16)(a0[j] - (float)h0);
            __bf16 h1 = (__bf16)a1[j];
            h[4 + j] = h1; l[4 + j] = (__bf16)(a1[j] - (float)h1);
        }
        *(bf16x8*)&xh[idx] = h;
        *(bf16x8*)&xl[idx] = l;
    } else if (g < 2304) {                // Wq -> [N,K] split
        int i = g - 2048;
        tsplit_body(Wq, Wqt_h, Wqt_l, 1024, 1024, (i & 15) * 64, (i >> 4) * 64, 1, tile);
    } else if (g < 2368) {                // Wkv -> split
        int i = g - 2304;
        tsplit_body(Wkv, Wkvt_h, Wkvt_l, 1024, 256, (i & 3) * 64, (i >> 2) * 64, 1, tile);
    } else if (g < 2432) {                // Wv -> trunc
        int i = g - 2368;
        tsplit_body(Wv, Wvt, nullptr, 256, 1024, (i & 15) * 64, (i >> 4) * 64, 0, tile);
    } else if (g < 2688) {                // Wo -> trunc
        int i = g - 2432;
        tsplit_body(Wo, Wot, nullptr, 1024, 1024, (i & 15) * 64, (i >> 4) * 64, 0, tile);
    } else if (g < 3716) {                // W2 = Wk_h @ Wkr (transposed split) + b2
        int o    = (g - 2688) * 256 + tid;
        int rowk = o >> 10, col = o & 1023;
        int h = col >> 6, d = col & 63;
        float acc = 0.0f;
        if (rowk < 256) {
#pragma unroll 8
            for (int j = 0; j < 64; ++j)
                acc += Wk[(size_t)rowk * DM + h * HD + j] * Wkr[j * HD + d];
            __bf16 hb = (__bf16)acc;
            W2th[(size_t)col * 256 + rowk] = hb;
            W2tl[(size_t)col * 256 + rowk] = (__bf16)(acc - (float)hb);
        } else {
#pragma unroll 8
            for (int j = 0; j < 64; ++j)
                acc += bk[h * HD + j] * Wkr[j * HD + d];
            b2[col] = acc;
        }
    } else {                              // RoPE cos/sin table [T_SEQ][32]
        int idx = (g - 3716) * 256 + tid;          // 0..65535
        int t = idx >> 5, d = idx & 31;
        float inv = powf(10000.0f, -(float)d * (1.0f / 32.0f));
        float sv, cv;
        sincosf((float)t * inv, &sv, &cv);         // bit-identical to old epilogue
        rtab[idx] = make_float2(cv, sv);
    }
}

// ================= 128x128-tile GEMM, async-pipelined K-loop =================
// A bf16 [M,K] (hi + optional lo), B bf16 [N,K] (hi + optional lo)
// OUTM: 0 bf16 | 1 fp32 | 2 dual split bf16
// EPI:  0 bias | 1 RoPE*QSCALE split-out (rtab table) | 2 bias then *t | 3 v->vtg
// K-loop: DOUBLE-BUFFERED gl2lds panels, ONE barrier per 32-K step.
// LDS layout per buf (32768 B): Ah @0, Al @8192, Bh @16384, Bl @24576.
// NOTE: never pass nullptr for a lo pointer with DUAL*=1 (r5-r7 bug).
// NOTE: branches of ONE dispatch must never write memory another branch reads.
// NOTE r4: 128x64 retile of gemm_o REGRESSED (+9 µs). Keep fat 128x128 tiles.
// NOTE r14: EPI=1 trig moved to prep-filled rtab (was 32 sincosf+32 powf per
// thread on-device — G13: trig-heavy epilogue turns VALU-bound).
template <int DUALA, int DUALB, int OUTM, int EPI>
__device__ __forceinline__
void gemm_body(char* smem,
               const __bf16* __restrict__ Ahi, const __bf16* __restrict__ Alo,
               const __bf16* __restrict__ Bhi, const __bf16* __restrict__ Blo,
               const float* __restrict__ bias, const float2* __restrict__ rtab,
               void* __restrict__ Cp, void* __restrict__ Cp2,
               int m0, int n0, int N, int K)
{
    const int tid  = threadIdx.x;
    const int w    = tid >> 6;
    const int lane = tid & 63;
    const int l16  = lane & 15;
    const int quad = lane >> 4;
    const int wy   = w >> 1, wx = w & 1;

    f32x4 acc[4][4];
#pragma unroll
    for (int i = 0; i < 4; ++i)
#pragma unroll
        for (int j = 0; j < 4; ++j) acc[i][j] = (f32x4)0.0f;

    auto stage = [&](int k0, int buf) {
        char* bb = smem + buf * 32768;
#pragma unroll
        for (int i = 0; i < 2; ++i) {
            int s = i * 256 + tid, row = s >> 2, c8 = (s & 3) * 8;
            size_t aoff = (size_t)(m0 + row) * K + k0 + c8;
            size_t boff = (size_t)(n0 + row) * K + k0 + c8;
            char*  dst  = bb + (row * 32 + c8) * 2;
            gl2lds(&Ahi[aoff], dst);
            if (DUALA) gl2lds(&Alo[aoff], dst + 8192);
            gl2lds(&Bhi[boff], dst + 16384);
            if (DUALB) gl2lds(&Blo[boff], dst + 24576);
        }
    };

    stage(0, 0);
    const int J = K >> 5;
    for (int j = 0; j < J; ++j) {
        __syncthreads();               // drains gl2lds for step j (all waves)
        if (j + 1 < J) stage((j + 1) << 5, (j + 1) & 1);   // overlaps compute

        const __bf16* Ah = (const __bf16*)(smem + (j & 1) * 32768);
        const __bf16* Al = Ah + 4096;
        const __bf16* Bh = Ah + 8192;
        const __bf16* Bl = Ah + 12288;

        bf16x8 bfh[4], bfl[4];
#pragma unroll
        for (int ct = 0; ct < 4; ++ct) {
            bfh[ct] = *(const bf16x8*)&Bh[(wx * 64 + ct * 16 + l16) * 32 + quad * 8];
            if (DUALB) bfl[ct] = *(const bf16x8*)&Bl[(wx * 64 + ct * 16 + l16) * 32 + quad * 8];
        }
#pragma unroll
        for (int mf = 0; mf < 4; ++mf) {
            bf16x8 ah = *(const bf16x8*)&Ah[(wy * 64 + mf * 16 + l16) * 32 + quad * 8];
            bf16x8 al;
            if (DUALA) al = *(const bf16x8*)&Al[(wy * 64 + mf * 16 + l16) * 32 + quad * 8];
#pragma unroll
            for (int ct = 0; ct < 4; ++ct) {
                acc[mf][ct] = mfma16(ah, bfh[ct], acc[mf][ct]);
                if (DUALA) acc[mf][ct] = mfma16(al, bfh[ct], acc[mf][ct]);
                if (DUALB) acc[mf][ct] = mfma16(ah, bfl[ct], acc[mf][ct]);
            }
        }
    }

    float bias_v[4];
#pragma unroll
    for (int ct = 0; ct < 4; ++ct)
        bias_v[ct] = bias ? bias[n0 + wx * 64 + ct * 16 + l16] : 0.0f;

    if (EPI == 1) {  // RoPE (q): pair (d, d+32) = (ct, ct+2); *QSCALE; split out
        __bf16* Chi = (__bf16*)Cp;
        __bf16* Clo = (__bf16*)Cp2;
#pragma unroll
        for (int mf = 0; mf < 4; ++mf) {
#pragma unroll
            for (int r = 0; r < 4; ++r) {
                int m = m0 + wy * 64 + mf * 16 + quad * 4 + r;
                int t = m & (T_SEQ - 1);
                const float2* row = &rtab[t * 32];
#pragma unroll
                for (int ct = 0; ct < 2; ++ct) {
                    int    d  = ct * 16 + l16;
                    float2 cs = row[d];                    // {cos, sin} from table
                    float lo = acc[mf][ct][r]     + bias_v[ct];
                    float hi = acc[mf][ct + 2][r] + bias_v[ct + 2];
                    float v0 = (lo * cs.x - hi * cs.y) * QSCALE;
                    float v1 = (hi * cs.x + lo * cs.y) * QSCALE;
                    size_t i0 = (size_t)m * N + n0 + wx * 64 + d;
                    size_t i1 = i0 + 32;
                    __bf16 h0 = (__bf16)v0, h1 = (__bf16)v1;
                    Chi[i0] = h0; Clo[i0] = (__bf16)(v0 - (float)h0);
                    Chi[i1] = h1; Clo[i1] = (__bf16)(v1 - (float)h1);
                }
            }
        }
    } else if (EPI == 3) {  // v: write vtg[bh][d][t] via per-wave LDS transpose
        __syncthreads();
        __bf16* vt = (__bf16*)(smem + w * 9216);   // [64][72]
#pragma unroll
        for (int mf = 0; mf < 4; ++mf)
#pragma unroll
            for (int ct = 0; ct < 4; ++ct)
#pragma unroll
                for (int r = 0; r < 4; ++r)
                    vt[(ct * 16 + l16) * 72 + mf * 16 + quad * 4 + r] =
                        (__bf16)(acc[mf][ct][r] + bias_v[ct]);
        const int bb   = m0 >> 11;
        const int head = (n0 + wx * 64) >> 6;
        const int bh   = bb * 16 + head;
        __bf16* out    = (__bf16*)Cp;
        size_t  gbase  = ((size_t)(bh * 64 + lane)) * T_SEQ + (m0 & (T_SEQ - 1)) + wy * 64;
#pragma unroll
        for (int j8 = 0; j8 < 8; ++j8)
            *(bf16x8*)&out[gbase + j8 * 8] = *(const bf16x8*)&vt[lane * 72 + j8 * 8];
    } else {
#pragma unroll
        for (int mf = 0; mf < 4; ++mf) {
#pragma unroll
            for (int r = 0; r < 4; ++r) {
                int   m     = m0 + wy * 64 + mf * 16 + quad * 4 + r;
                float scale = (EPI == 2) ? (float)(m & (T_SEQ - 1)) : 1.0f;
#pragma unroll
                for (int ct = 0; ct < 4; ++ct) {
                    float  v   = (acc[mf][ct][r] + bias_v[ct]) * scale;
                    size_t idx = (size_t)m * N + n0 + wx * 64 + ct * 16 + l16;
                    if (OUTM == 1)      ((float*)Cp)[idx]  = v;
                    else if (OUTM == 0) ((__bf16*)Cp)[idx] = (__bf16)v;
                    else {
                        __bf16 hb = (__bf16)v;
                        ((__bf16*)Cp)[idx]  = hb;
                        ((__bf16*)Cp2)[idx] = (__bf16)(v - (float)hb);
                    }
                }
            }
        }
    }
}

// merged kv + q gemm: grid (10, 32) = 320 blocks (kv first so it fills early)
__global__ __launch_bounds__(256)
void gemm_qkv(const __bf16* xh, const __bf16* xl,
              const __bf16* Wqt_h, const __bf16* Wqt_l, const float* bq,
              const float2* rtab, __bf16* qhi, __bf16* qlo,
              const __bf16* Wkvt_h, const __bf16* Wkvt_l, const float* bkv,
              __bf16* kvhi, __bf16* kvlo)
{
    __shared__ __attribute__((aligned(16))) char smem[65536];
    const int m0 = blockIdx.y * 128;
    if (blockIdx.x < 2)
        gemm_body<1, 1, 2, 0>(smem, xh, xl, Wkvt_h, Wkvt_l, bkv, nullptr, kvhi, kvlo,
                              m0, blockIdx.x * 128, 256, 1024);
    else
        gemm_body<1, 1, 2, 1>(smem, xh, xl, Wqt_h, Wqt_l, bq, rtab, qhi, qlo,
                              m0, (blockIdx.x - 2) * 128, 1024, 1024);
}

// merged k + v gemm: grid (16, 32) = 512 blocks = 2/CU. Safe merge: v writes
// vtg (overlays xlo) and no branch here reads xlo (q is in the prior dispatch).
__global__ __launch_bounds__(256)
void gemm_kv2(const __bf16* kvhi, const __bf16* kvlo,
              const __bf16* W2th, const __bf16* W2tl, const float* b2,
              __bf16* khi, __bf16* klo,
              const __bf16* Wvt, const float* bv, __bf16* vtg)
{
    __shared__ __attribute__((aligned(16))) char smem[65536];
    const int m0 = blockIdx.y * 128;
    if (blockIdx.x < 8)
        gemm_body<1, 1, 2, 2>(smem, kvhi, kvlo, W2th, W2tl, b2, nullptr, khi, klo,
                              m0, blockIdx.x * 128, 1024, 256);
    else
        gemm_body<1, 0, 0, 3>(smem, kvhi, kvlo, Wvt, Wvt, bv, nullptr, vtg, nullptr,
                              m0, (blockIdx.x - 8) * 128, 1024, 256);
}

// o gemm: grid (8, 32) — r3 version restored (r4's 128x64 retile regressed)
__global__ __launch_bounds__(256)
void gemm_o(const __bf16* ybb, const __bf16* Wot, const float* bo, float* out)
{
    __shared__ __attribute__((aligned(16))) char smem[65536];
    gemm_body<0, 0, 1, 0>(smem, ybb, ybb, Wot, Wot, bo, nullptr, out, nullptr,
                          blockIdx.y * 128, blockIdx.x * 128, 1024, 1024);
}

// ================= flash attention v9 + lean defer-max =======================
// v9 (verified 70.2-71.3 µs): equal-length blocks, gl2lds K/V + both-sides XOR
// swizzle, max-tree. r12 lesson: paired-frag ILP regressed — only REMOVING
// work from the per-step serial chain helps.
// r14: LEAN defer-max (T13 retry, unconfounded — r2's fail bundled T5 +
// duplicated body). Shared exp2 loop; wave-uniform __all picks mn; only the
// non-defer path pays alpha (1 exp2 + 16 mults + m_i update). With position-
// scaled K, per-step max growth << 8 -> most steps defer. r2 empirically
// showed defer-max leaves absmax at 0.00390625 on this data.
// Prediction: dur 71.3 -> 68.5-70.5, VGPR ~88, CONF ~1.72M.
#define PSP 72
__global__ __launch_bounds__(256, 2)
void attn_v9(const __bf16* __restrict__ qhi, const __bf16* __restrict__ qlo,
             const __bf16* __restrict__ khi, const __bf16* __restrict__ klo,
             const __bf16* __restrict__ vtg, __bf16* __restrict__ yb)
{
    __shared__ __attribute__((aligned(16))) __bf16 Kh2[2][64 * 64];
    __shared__ __attribute__((aligned(16))) __bf16 Kl2[2][64 * 64];
    __shared__ __attribute__((aligned(16))) __bf16 Vt2[2][64 * 64];   // [d][key]
    __shared__ __attribute__((aligned(16))) __bf16 Pw[4][16 * PSP];   // [wave][qrow][key]

    const int tid  = threadIdx.x;
    const int w    = tid >> 6;
    const int lane = tid & 63;
    const int l16  = lane & 15;
    const int quad = lane >> 4;

    const int g  = blockIdx.x;
    const int bh = g & 31, a = g >> 5;      // a in 0..15; same-bh blocks share an XCD
    const int b  = bh >> 4, h = bh & 15;

    const int sr0 = tid >> 3, sc = tid & 7;  // staging: row-within-half, col8
    const int sw  = l16 & 7;                 // read-side swizzle key

    // issue one 64-key step's K(hi,lo)+V into buf via direct gl2lds (6/thread)
    auto stage = [&](int j0, int buf) {
#pragma unroll
        for (int it = 0; it < 2; ++it) {
            int r   = it * 32 + sr0;
            int c8g = sc ^ (r & 7);            // inverse source swizzle
            int d0  = it * 2048 + tid * 8;     // linear dest (lane*16 bytes)
            gl2lds(&khi[(size_t)(b * T_SEQ + j0 + r) * DM + h * HD + c8g * 8], &Kh2[buf][d0]);
            gl2lds(&klo[(size_t)(b * T_SEQ + j0 + r) * DM + h * HD + c8g * 8], &Kl2[buf][d0]);
            gl2lds(&vtg[(size_t)(bh * HD + r) * T_SEQ + j0 + c8g * 8],         &Vt2[buf][d0]);
        }
    };

    for (int ph = 0; ph < 2; ++ph) {
        const int u  = ph ? a : (31 - a);   // long tile first, then short
        const int q0 = u * 64;

        // Q B-frag for this 64-row tile (pre-scaled by QSCALE), 2 k-halves
        bf16x8 qh[2], ql[2];
        {
            const int    qr   = q0 + 16 * w + l16;
            const size_t qoff = (size_t)(b * T_SEQ + qr) * DM + h * HD;
#pragma unroll
            for (int s = 0; s < 2; ++s) {
                qh[s] = *(const bf16x8*)&qhi[qoff + s * 32 + quad * 8];
                ql[s] = *(const bf16x8*)&qlo[qoff + s * 32 + quad * 8];
            }
        }

        f32x4 o[4];
#pragma unroll
        for (int i = 0; i < 4; ++i) o[i] = (f32x4)0.0f;
        float m_i = -1e30f, l_i = 0.f;

        __syncthreads();   // all waves done reading LDS from previous phase
        stage(0, 0);

        for (int j0 = 0; j0 <= q0; j0 += 64) {
            const int  cur = (j0 >> 6) & 1;
            __syncthreads();            // drains gl2lds(buf[cur]); buf[cur^1] readers done
            if (j0 + 64 <= q0) stage(j0 + 64, cur ^ 1);   // overlaps compute

            const __bf16* Kh = Kh2[cur];
            const __bf16* Kl = Kl2[cur];
            const __bf16* Vt = Vt2[cur];

            // S^T = K Q^T: rows=keys (kc,quad,reg), cols=qrows (l16)
            f32x4 sa[4];
#pragma unroll
            for (int i = 0; i < 4; ++i) sa[i] = (f32x4)0.0f;
#pragma unroll
            for (int s = 0; s < 2; ++s) {
                const int c8s = ((s * 4 + quad) ^ sw) * 8;   // swizzled col
#pragma unroll
                for (int kc = 0; kc < 4; ++kc) {
                    bf16x8 kh = *(const bf16x8*)&Kh[(kc * 16 + l16) * 64 + c8s];
                    bf16x8 kv = *(const bf16x8*)&Kl[(kc * 16 + l16) * 64 + c8s];
                    sa[kc] = mfma16(kh, qh[s], sa[kc]);
                    sa[kc] = mfma16(kv, qh[s], sa[kc]);
                    sa[kc] = mfma16(kh, ql[s], sa[kc]);
                }
            }

            // causal mask + online softmax (cross-quad shfl reductions)
            const int  qr   = q0 + 16 * w + l16;
            const bool need = (j0 + 63 > q0 + 16 * w);
            if (need) {
#pragma unroll
                for (int kc = 0; kc < 4; ++kc)
#pragma unroll
                    for (int r = 0; r < 4; ++r)
                        if (j0 + kc * 16 + quad * 4 + r > qr) sa[kc][r] = -1e30f;
            }
            // depth-4 pairwise max tree (exact)
            float t0 = fmaxf(fmaxf(sa[0][0], sa[0][1]), fmaxf(sa[0][2], sa[0][3]));
            float t1 = fmaxf(fmaxf(sa[1][0], sa[1][1]), fmaxf(sa[1][2], sa[1][3]));
            float t2 = fmaxf(fmaxf(sa[2][0], sa[2][1]), fmaxf(sa[2][2], sa[2][3]));
            float t3 = fmaxf(fmaxf(sa[3][0], sa[3][1]), fmaxf(sa[3][2], sa[3][3]));
            float mx = fmaxf(fmaxf(t0, t1), fmaxf(t2, t3));
            mx = fmaxf(mx, __shfl_xor(mx, 16));
            mx = fmaxf(mx, __shfl_xor(mx, 32));
            // lean defer-max: keep old max when no row grew by >8 exp2-units
            // (P bounded by 2^8 — bf16-safe; f32 accum unaffected)
            const bool defer = __all(mx - m_i <= 8.0f);
            const float mn   = defer ? m_i : fmaxf(fmaxf(m_i, mx), -1e20f);
            float rs = 0.f;
            __bf16* pw = &Pw[w][0];
#pragma unroll
            for (int kc = 0; kc < 4; ++kc) {
                float p0 = exp2f(sa[kc][0] - mn);
                float p1 = exp2f(sa[kc][1] - mn);
                float p2 = exp2f(sa[kc][2] - mn);
                float p3 = exp2f(sa[kc][3] - mn);
                rs += (p0 + p1) + (p2 + p3);
                bf16x4 pk = { (__bf16)p0, (__bf16)p1, (__bf16)p2, (__bf16)p3 };
                *(bf16x4*)&pw[l16 * PSP + kc * 16 + quad * 4] = pk;
            }
            rs += __shfl_xor(rs, 16);
            rs += __shfl_xor(rs, 32);
            if (defer) {
                l_i += rs;
            } else {
                float alpha = exp2f(m_i - mn);
                l_i = l_i * alpha + rs;
#pragma unroll
                for (int dc = 0; dc < 4; ++dc) o[dc] *= alpha;
                m_i = mn;
            }

            // O^T += V^T P^T: rows=d (dc,quad,reg), cols=qrows (l16)
#pragma unroll
            for (int s = 0; s < 2; ++s) {
                const int c8s = ((s * 4 + quad) ^ sw) * 8;
                bf16x8 pb = *(const bf16x8*)&pw[l16 * PSP + s * 32 + quad * 8];
#pragma unroll
                for (int dc = 0; dc < 4; ++dc) {
                    bf16x8 va = *(const bf16x8*)&Vt[(dc * 16 + l16) * 64 + c8s];
                    o[dc] = mfma16(va, pb, o[dc]);
                }
            }
        }

        // epilogue: normalize, transpose via per-wave P buffer, coalesced store
        {
            float   invl = 1.0f / l_i;
            __bf16* pw   = &Pw[w][0];
#pragma unroll
            for (int dc = 0; dc < 4; ++dc) {
                bf16x4 ov = { (__bf16)(o[dc][0] * invl), (__bf16)(o[dc][1] * invl),
                              (__bf16)(o[dc][2] * invl), (__bf16)(o[dc][3] * invl) };
                *(bf16x4*)&pw[l16 * PSP + dc * 16 + quad * 4] = ov;
            }
            const int qrl  = lane >> 2;          // 0..15
            const int dch  = (lane & 3) * 16;    // 0,16,32,48
            const int qrow = q0 + 16 * w + qrl;
            const __bf16* src = &pw[qrl * PSP + dch];
            __bf16*       dst = &yb[(size_t)(b * T_SEQ + qrow) * DM + h * HD + dch];
            *(bf16x8*)dst       = *(const bf16x8*)src;
            *(bf16x8*)(dst + 8) = *(const bf16x8*)(src + 8);
        }
    }
}

extern "C" void kernel_launch(void* const* d_in, const int* in_sizes, int n_in,
                              void* d_out, int out_size, void* d_ws, size_t ws_size,
                              hipStream_t stream)
{
    (void)in_sizes; (void)n_in; (void)out_size; (void)ws_size;

    const float* x   = (const float*)d_in[0];
    const float* Wq  = (const float*)d_in[2];
    const float* bq  = (const float*)d_in[3];
    const float* Wkv = (const float*)d_in[4];
    const float* bkv = (const float*)d_in[5];
    const float* Wk  = (const float*)d_in[6];
    const float* bk  = (const float*)d_in[7];
    const float* Wv  = (const float*)d_in[8];
    const float* bv  = (const float*)d_in[9];
    const float* Wo  = (const float*)d_in[10];
    const float* bo  = (const float*)d_in[11];
    const float* Wkr = (const float*)d_in[12];

    const int    BT = 2 * T_SEQ;   // 4096
    const size_t MB = 1024 * 1024;
    char* base = (char*)d_ws;

    __bf16* xhi    = (__bf16*)(base +  0 * MB);
    __bf16* xlo    = (__bf16*)(base +  8 * MB);
    __bf16* qhi    = (__bf16*)(base + 16 * MB);
    __bf16* qlo    = (__bf16*)(base + 24 * MB);
    __bf16* Wqt_h  = (__bf16*)(base + 32 * MB);
    __bf16* Wqt_l  = (__bf16*)(base + 34 * MB);
    __bf16* Wkvt_h = (__bf16*)(base + 36 * MB);
    __bf16* Wkvt_l = (__bf16*)(base + 37 * MB);
    __bf16* kvhi   = (__bf16*)(base + 38 * MB);
    __bf16* kvlo   = (__bf16*)(base + 40 * MB);
    __bf16* W2t_h  = (__bf16*)(base + 42 * MB);
    __bf16* W2t_l  = (__bf16*)(base + 42 * MB + 512 * 1024);
    __bf16* Wvt    = (__bf16*)(base + 43 * MB);
    __bf16* Wot    = (__bf16*)(base + 43 * MB + 512 * 1024);
    float*  b2     = (float*) (base + 45 * MB + 512 * 1024);
    float2* rtab   = (float2*)(base + 46 * MB);               // 512 KB cos/sin table
    __bf16* vtg    = (__bf16*)(base +  8 * MB);               // overlays xlo (dead after gemm_qkv)
    __bf16* ybb    = (__bf16*)(base +  0 * MB);               // overlays xhi (dead after gemm_qkv)
    __bf16* khi    = (__bf16*)d_out;                          // d_out as scratch
    __bf16* klo    = (__bf16*)d_out + (size_t)BT * DM;        // overwritten by o gemm

    dim3 blk(256);
    prep<<<3972, blk, 0, stream>>>(x, Wq, Wkv, Wv, Wo, Wk, Wkr, bk,
                                   xhi, xlo, Wqt_h, Wqt_l, Wkvt_h, Wkvt_l,
                                   Wvt, Wot, W2t_h, W2t_l, b2, rtab);
    gemm_qkv<<<dim3(10, 32), blk, 0, stream>>>(xhi, xlo, Wqt_h, Wqt_l, bq, rtab, qhi, qlo,
                                               Wkvt_h, Wkvt_l, bkv, kvhi, kvlo);
    gemm_kv2<<<dim3(16, 32), blk, 0, stream>>>(kvhi, kvlo, W2t_h, W2t_l, b2,
                                               khi, klo, Wvt, bv, vtg);
    attn_v9<<<512, blk, 0, stream>>>(qhi, qlo, khi, klo, vtg, ybb);
    gemm_o<<<dim3(8, 32), blk, 0, stream>>>(ybb, Wot, bo, (float*)d_out);
}

// Round 21
// 255.791 us; speedup vs baseline: 1.0613x; 1.0017x over previous
//
#include <hip/hip_runtime.h>
#include <hip/hip_bf16.h>
#include <math.h>

typedef __bf16 bf16x8 __attribute__((ext_vector_type(8)));
typedef __bf16 bf16x4 __attribute__((ext_vector_type(4)));
typedef float  f32x4  __attribute__((ext_vector_type(4)));

#define T_SEQ 2048
#define NH    16
#define HD    64
#define DM    1024
// softmax logits pre-scaled by 1/sqrt(64) * log2(e) so we can use exp2
#define QSCALE 0.18033688011112043f

__device__ __forceinline__ f32x4 mfma16(bf16x8 a, bf16x8 b, f32x4 c) {
    return __builtin_amdgcn_mfma_f32_16x16x32_bf16(a, b, c, 0, 0, 0);
}

// async global->LDS, 16B per lane. LDS dest is wave-uniform base + lane*16
// (our staging layout is exactly that). Barrier's implicit vmcnt(0) drains.
__device__ __forceinline__ void gl2lds(const void* g, void* l) {
    __builtin_amdgcn_global_load_lds(
        (const __attribute__((address_space(1))) void*)g,
        (__attribute__((address_space(3))) void*)l, 16, 0, 0);
}

// ================= prep (one dispatch) =================
__device__ __forceinline__ void tsplit_body(const float* __restrict__ in,
                                            __bf16* __restrict__ oh, __bf16* __restrict__ ol,
                                            int K, int N, int n0, int k0, int SPLIT,
                                            float* tile /* [64][65] LDS */)
{
    const int tid = threadIdx.x;
#pragma unroll
    for (int it = 0; it < 2; ++it) {
        int r = it * 32 + (tid >> 3), c8 = (tid & 7) * 8;
        f32x4 a0 = *(const f32x4*)&in[(size_t)(k0 + r) * N + n0 + c8];
        f32x4 a1 = *(const f32x4*)&in[(size_t)(k0 + r) * N + n0 + c8 + 4];
#pragma unroll
        for (int j = 0; j < 4; ++j) { tile[r * 65 + c8 + j] = a0[j]; tile[r * 65 + c8 + 4 + j] = a1[j]; }
    }
    __syncthreads();
    const int n = tid >> 2, kb = (tid & 3) * 16;
    bf16x8 h0, h1, l0, l1;
#pragma unroll
    for (int j = 0; j < 8; ++j) {
        float v0 = tile[(kb + j) * 65 + n], v1 = tile[(kb + 8 + j) * 65 + n];
        __bf16 hb0 = (__bf16)v0, hb1 = (__bf16)v1;
        h0[j] = hb0; h1[j] = hb1;
        if (SPLIT) { l0[j] = (__bf16)(v0 - (float)hb0); l1[j] = (__bf16)(v1 - (float)hb1); }
    }
    size_t o = (size_t)(n0 + n) * K + k0 + kb;
    *(bf16x8*)&oh[o] = h0; *(bf16x8*)&oh[o + 8] = h1;
    if (SPLIT) { *(bf16x8*)&ol[o] = l0; *(bf16x8*)&ol[o + 8] = l1; }
}

__global__ __launch_bounds__(256)
void prep(const float* __restrict__ x, const float* __restrict__ Wq,
          const float* __restrict__ Wkv, const float* __restrict__ Wv,
          const float* __restrict__ Wo, const float* __restrict__ Wk,
          const float* __restrict__ Wkr, const float* __restrict__ bk,
          __bf16* xh, __bf16* xl, __bf16* Wqt_h, __bf16* Wqt_l,
          __bf16* Wkvt_h, __bf16* Wkvt_l, __bf16* Wvt, __bf16* Wot,
          __bf16* W2th, __bf16* W2tl, float* b2, float2* rtab)
{
    __shared__ float tile[64 * 65];
    const int g = blockIdx.x, tid = threadIdx.x;
    if (g < 2048) {                       // split x -> xh/xl
        size_t idx = ((size_t)g * 256 + tid) * 8;
        f32x4 a0 = *(const f32x4*)&x[idx];
        f32x4 a1 = *(const f32x4*)&x[idx + 4];
        bf16x8 h, l;
#pragma unroll
        for (int j = 0; j < 4; ++j) {
            __bf16 h0 = (__bf16)a0[j];
            h[j]     = h0; l[j]     = (__bf16)(a0[j] - (float)h0);
            __bf16 h1 = (__bf16)a1[j];
            h[4 + j] = h1; l[4 + j] = (__bf16)(a1[j] - (float)h1);
        }
        *(bf16x8*)&xh[idx] = h;
        *(bf16x8*)&xl[idx] = l;
    } else if (g < 2304) {                // Wq -> [N,K] split
        int i = g - 2048;
        tsplit_body(Wq, Wqt_h, Wqt_l, 1024, 1024, (i & 15) * 64, (i >> 4) * 64, 1, tile);
    } else if (g < 2368) {                // Wkv -> split
        int i = g - 2304;
        tsplit_body(Wkv, Wkvt_h, Wkvt_l, 1024, 256, (i & 3) * 64, (i >> 2) * 64, 1, tile);
    } else if (g < 2432) {                // Wv -> trunc
        int i = g - 2368;
        tsplit_body(Wv, Wvt, nullptr, 256, 1024, (i & 15) * 64, (i >> 4) * 64, 0, tile);
    } else if (g < 2688) {                // Wo -> trunc
        int i = g - 2432;
        tsplit_body(Wo, Wot, nullptr, 1024, 1024, (i & 15) * 64, (i >> 4) * 64, 0, tile);
    } else if (g < 3716) {                // W2 = Wk_h @ Wkr (transposed split) + b2
        int o    = (g - 2688) * 256 + tid;
        int rowk = o >> 10, col = o & 1023;
        int h = col >> 6, d = col & 63;
        float acc = 0.0f;
        if (rowk < 256) {
#pragma unroll 8
            for (int j = 0; j < 64; ++j)
                acc += Wk[(size_t)rowk * DM + h * HD + j] * Wkr[j * HD + d];
            __bf16 hb = (__bf16)acc;
            W2th[(size_t)col * 256 + rowk] = hb;
            W2tl[(size_t)col * 256 + rowk] = (__bf16)(acc - (float)hb);
        } else {
#pragma unroll 8
            for (int j = 0; j < 64; ++j)
                acc += bk[h * HD + j] * Wkr[j * HD + d];
            b2[col] = acc;
        }
    } else {                              // RoPE cos/sin table [T_SEQ][32]
        int idx = (g - 3716) * 256 + tid;          // 0..65535
        int t = idx >> 5, d = idx & 31;
        float inv = powf(10000.0f, -(float)d * (1.0f / 32.0f));
        float sv, cv;
        sincosf((float)t * inv, &sv, &cv);         // bit-identical to old epilogue
        rtab[idx] = make_float2(cv, sv);
    }
}

// ================= 128x128-tile GEMM, async-pipelined K-loop =================
// A bf16 [M,K] (hi + optional lo), B bf16 [N,K] (hi + optional lo)
// OUTM: 0 bf16 | 1 fp32 | 2 dual split bf16
// EPI:  0 bias | 1 RoPE*QSCALE split-out (rtab table) | 2 bias then *t | 3 v->vtg
// K-loop: DOUBLE-BUFFERED gl2lds panels, ONE barrier per 32-K step.
// LDS layout per buf (32768 B): Ah @0, Al @8192, Bh @16384, Bl @24576.
// NOTE: never pass nullptr for a lo pointer with DUAL*=1 (r5-r7 bug).
// NOTE: branches of ONE dispatch must never write memory another branch reads.
// NOTE r4: 128x64 retile of gemm_o REGRESSED (+9 µs). Keep fat 128x128 tiles.
// NOTE r19: rtab (prep-filled trig table) CONFIRMED ~-6.6 µs on gemm_qkv.
template <int DUALA, int DUALB, int OUTM, int EPI>
__device__ __forceinline__
void gemm_body(char* smem,
               const __bf16* __restrict__ Ahi, const __bf16* __restrict__ Alo,
               const __bf16* __restrict__ Bhi, const __bf16* __restrict__ Blo,
               const float* __restrict__ bias, const float2* __restrict__ rtab,
               void* __restrict__ Cp, void* __restrict__ Cp2,
               int m0, int n0, int N, int K)
{
    const int tid  = threadIdx.x;
    const int w    = tid >> 6;
    const int lane = tid & 63;
    const int l16  = lane & 15;
    const int quad = lane >> 4;
    const int wy   = w >> 1, wx = w & 1;

    f32x4 acc[4][4];
#pragma unroll
    for (int i = 0; i < 4; ++i)
#pragma unroll
        for (int j = 0; j < 4; ++j) acc[i][j] = (f32x4)0.0f;

    auto stage = [&](int k0, int buf) {
        char* bb = smem + buf * 32768;
#pragma unroll
        for (int i = 0; i < 2; ++i) {
            int s = i * 256 + tid, row = s >> 2, c8 = (s & 3) * 8;
            size_t aoff = (size_t)(m0 + row) * K + k0 + c8;
            size_t boff = (size_t)(n0 + row) * K + k0 + c8;
            char*  dst  = bb + (row * 32 + c8) * 2;
            gl2lds(&Ahi[aoff], dst);
            if (DUALA) gl2lds(&Alo[aoff], dst + 8192);
            gl2lds(&Bhi[boff], dst + 16384);
            if (DUALB) gl2lds(&Blo[boff], dst + 24576);
        }
    };

    stage(0, 0);
    const int J = K >> 5;
    for (int j = 0; j < J; ++j) {
        __syncthreads();               // drains gl2lds for step j (all waves)
        if (j + 1 < J) stage((j + 1) << 5, (j + 1) & 1);   // overlaps compute

        const __bf16* Ah = (const __bf16*)(smem + (j & 1) * 32768);
        const __bf16* Al = Ah + 4096;
        const __bf16* Bh = Ah + 8192;
        const __bf16* Bl = Ah + 12288;

        bf16x8 bfh[4], bfl[4];
#pragma unroll
        for (int ct = 0; ct < 4; ++ct) {
            bfh[ct] = *(const bf16x8*)&Bh[(wx * 64 + ct * 16 + l16) * 32 + quad * 8];
            if (DUALB) bfl[ct] = *(const bf16x8*)&Bl[(wx * 64 + ct * 16 + l16) * 32 + quad * 8];
        }
#pragma unroll
        for (int mf = 0; mf < 4; ++mf) {
            bf16x8 ah = *(const bf16x8*)&Ah[(wy * 64 + mf * 16 + l16) * 32 + quad * 8];
            bf16x8 al;
            if (DUALA) al = *(const bf16x8*)&Al[(wy * 64 + mf * 16 + l16) * 32 + quad * 8];
#pragma unroll
            for (int ct = 0; ct < 4; ++ct) {
                acc[mf][ct] = mfma16(ah, bfh[ct], acc[mf][ct]);
                if (DUALA) acc[mf][ct] = mfma16(al, bfh[ct], acc[mf][ct]);
                if (DUALB) acc[mf][ct] = mfma16(ah, bfl[ct], acc[mf][ct]);
            }
        }
    }

    float bias_v[4];
#pragma unroll
    for (int ct = 0; ct < 4; ++ct)
        bias_v[ct] = bias ? bias[n0 + wx * 64 + ct * 16 + l16] : 0.0f;

    if (EPI == 1) {  // RoPE (q): pair (d, d+32) = (ct, ct+2); *QSCALE; split out
        __bf16* Chi = (__bf16*)Cp;
        __bf16* Clo = (__bf16*)Cp2;
#pragma unroll
        for (int mf = 0; mf < 4; ++mf) {
#pragma unroll
            for (int r = 0; r < 4; ++r) {
                int m = m0 + wy * 64 + mf * 16 + quad * 4 + r;
                int t = m & (T_SEQ - 1);
                const float2* row = &rtab[t * 32];
#pragma unroll
                for (int ct = 0; ct < 2; ++ct) {
                    int    d  = ct * 16 + l16;
                    float2 cs = row[d];                    // {cos, sin} from table
                    float lo = acc[mf][ct][r]     + bias_v[ct];
                    float hi = acc[mf][ct + 2][r] + bias_v[ct + 2];
                    float v0 = (lo * cs.x - hi * cs.y) * QSCALE;
                    float v1 = (hi * cs.x + lo * cs.y) * QSCALE;
                    size_t i0 = (size_t)m * N + n0 + wx * 64 + d;
                    size_t i1 = i0 + 32;
                    __bf16 h0 = (__bf16)v0, h1 = (__bf16)v1;
                    Chi[i0] = h0; Clo[i0] = (__bf16)(v0 - (float)h0);
                    Chi[i1] = h1; Clo[i1] = (__bf16)(v1 - (float)h1);
                }
            }
        }
    } else if (EPI == 3) {  // v: write vtg[bh][d][t] via per-wave LDS transpose
        __syncthreads();
        __bf16* vt = (__bf16*)(smem + w * 9216);   // [64][72]
#pragma unroll
        for (int mf = 0; mf < 4; ++mf)
#pragma unroll
            for (int ct = 0; ct < 4; ++ct)
#pragma unroll
                for (int r = 0; r < 4; ++r)
                    vt[(ct * 16 + l16) * 72 + mf * 16 + quad * 4 + r] =
                        (__bf16)(acc[mf][ct][r] + bias_v[ct]);
        const int bb   = m0 >> 11;
        const int head = (n0 + wx * 64) >> 6;
        const int bh   = bb * 16 + head;
        __bf16* out    = (__bf16*)Cp;
        size_t  gbase  = ((size_t)(bh * 64 + lane)) * T_SEQ + (m0 & (T_SEQ - 1)) + wy * 64;
#pragma unroll
        for (int j8 = 0; j8 < 8; ++j8)
            *(bf16x8*)&out[gbase + j8 * 8] = *(const bf16x8*)&vt[lane * 72 + j8 * 8];
    } else {
#pragma unroll
        for (int mf = 0; mf < 4; ++mf) {
#pragma unroll
            for (int r = 0; r < 4; ++r) {
                int   m     = m0 + wy * 64 + mf * 16 + quad * 4 + r;
                float scale = (EPI == 2) ? (float)(m & (T_SEQ - 1)) : 1.0f;
#pragma unroll
                for (int ct = 0; ct < 4; ++ct) {
                    float  v   = (acc[mf][ct][r] + bias_v[ct]) * scale;
                    size_t idx = (size_t)m * N + n0 + wx * 64 + ct * 16 + l16;
                    if (OUTM == 1)      ((float*)Cp)[idx]  = v;
                    else if (OUTM == 0) ((__bf16*)Cp)[idx] = (__bf16)v;
                    else {
                        __bf16 hb = (__bf16)v;
                        ((__bf16*)Cp)[idx]  = hb;
                        ((__bf16*)Cp2)[idx] = (__bf16)(v - (float)hb);
                    }
                }
            }
        }
    }
}

// merged kv + q gemm: grid (10, 32) = 320 blocks (kv first so it fills early)
__global__ __launch_bounds__(256)
void gemm_qkv(const __bf16* xh, const __bf16* xl,
              const __bf16* Wqt_h, const __bf16* Wqt_l, const float* bq,
              const float2* rtab, __bf16* qhi, __bf16* qlo,
              const __bf16* Wkvt_h, const __bf16* Wkvt_l, const float* bkv,
              __bf16* kvhi, __bf16* kvlo)
{
    __shared__ __attribute__((aligned(16))) char smem[65536];
    const int m0 = blockIdx.y * 128;
    if (blockIdx.x < 2)
        gemm_body<1, 1, 2, 0>(smem, xh, xl, Wkvt_h, Wkvt_l, bkv, nullptr, kvhi, kvlo,
                              m0, blockIdx.x * 128, 256, 1024);
    else
        gemm_body<1, 1, 2, 1>(smem, xh, xl, Wqt_h, Wqt_l, bq, rtab, qhi, qlo,
                              m0, (blockIdx.x - 2) * 128, 1024, 1024);
}

// merged k + v gemm: grid (16, 32) = 512 blocks = 2/CU. Safe merge: v writes
// vtg (overlays xlo) and no branch here reads xlo (q is in the prior dispatch).
__global__ __launch_bounds__(256)
void gemm_kv2(const __bf16* kvhi, const __bf16* kvlo,
              const __bf16* W2th, const __bf16* W2tl, const float* b2,
              __bf16* khi, __bf16* klo,
              const __bf16* Wvt, const float* bv, __bf16* vtg)
{
    __shared__ __attribute__((aligned(16))) char smem[65536];
    const int m0 = blockIdx.y * 128;
    if (blockIdx.x < 8)
        gemm_body<1, 1, 2, 2>(smem, kvhi, kvlo, W2th, W2tl, b2, nullptr, khi, klo,
                              m0, blockIdx.x * 128, 1024, 256);
    else
        gemm_body<1, 0, 0, 3>(smem, kvhi, kvlo, Wvt, Wvt, bv, nullptr, vtg, nullptr,
                              m0, (blockIdx.x - 8) * 128, 1024, 256);
}

// o gemm: grid (8, 32) — r3 version restored (r4's 128x64 retile regressed)
__global__ __launch_bounds__(256)
void gemm_o(const __bf16* ybb, const __bf16* Wot, const float* bo, float* out)
{
    __shared__ __attribute__((aligned(16))) char smem[65536];
    gemm_body<0, 0, 1, 0>(smem, ybb, ybb, Wot, Wot, bo, nullptr, out, nullptr,
                          blockIdx.y * 128, blockIdx.x * 128, 1024, 1024);
}

// ================= flash attention v9 (defer-max STRIPPED, r19) ==============
// v9: equal-length blocks, gl2lds K/V + both-sides XOR swizzle, max-tree.
// History: r12 paired-frag ILP regressed (77.7); r14 lean defer-max measured
// 73.2 vs r13's 71.3 without -> T13 closed as neutral-to-negative on this
// problem (causal-diagonal max growth defeats THR=8). This is r13's verified
// 71.3 µs attn body, unchanged.
// Prediction: attn ~71, total ~254 (keeps r19's rtab win).
#define PSP 72
__global__ __launch_bounds__(256, 2)
void attn_v9(const __bf16* __restrict__ qhi, const __bf16* __restrict__ qlo,
             const __bf16* __restrict__ khi, const __bf16* __restrict__ klo,
             const __bf16* __restrict__ vtg, __bf16* __restrict__ yb)
{
    __shared__ __attribute__((aligned(16))) __bf16 Kh2[2][64 * 64];
    __shared__ __attribute__((aligned(16))) __bf16 Kl2[2][64 * 64];
    __shared__ __attribute__((aligned(16))) __bf16 Vt2[2][64 * 64];   // [d][key]
    __shared__ __attribute__((aligned(16))) __bf16 Pw[4][16 * PSP];   // [wave][qrow][key]

    const int tid  = threadIdx.x;
    const int w    = tid >> 6;
    const int lane = tid & 63;
    const int l16  = lane & 15;
    const int quad = lane >> 4;

    const int g  = blockIdx.x;
    const int bh = g & 31, a = g >> 5;      // a in 0..15; same-bh blocks share an XCD
    const int b  = bh >> 4, h = bh & 15;

    const int sr0 = tid >> 3, sc = tid & 7;  // staging: row-within-half, col8
    const int sw  = l16 & 7;                 // read-side swizzle key

    // issue one 64-key step's K(hi,lo)+V into buf via direct gl2lds (6/thread)
    auto stage = [&](int j0, int buf) {
#pragma unroll
        for (int it = 0; it < 2; ++it) {
            int r   = it * 32 + sr0;
            int c8g = sc ^ (r & 7);            // inverse source swizzle
            int d0  = it * 2048 + tid * 8;     // linear dest (lane*16 bytes)
            gl2lds(&khi[(size_t)(b * T_SEQ + j0 + r) * DM + h * HD + c8g * 8], &Kh2[buf][d0]);
            gl2lds(&klo[(size_t)(b * T_SEQ + j0 + r) * DM + h * HD + c8g * 8], &Kl2[buf][d0]);
            gl2lds(&vtg[(size_t)(bh * HD + r) * T_SEQ + j0 + c8g * 8],         &Vt2[buf][d0]);
        }
    };

    for (int ph = 0; ph < 2; ++ph) {
        const int u  = ph ? a : (31 - a);   // long tile first, then short
        const int q0 = u * 64;

        // Q B-frag for this 64-row tile (pre-scaled by QSCALE), 2 k-halves
        bf16x8 qh[2], ql[2];
        {
            const int    qr   = q0 + 16 * w + l16;
            const size_t qoff = (size_t)(b * T_SEQ + qr) * DM + h * HD;
#pragma unroll
            for (int s = 0; s < 2; ++s) {
                qh[s] = *(const bf16x8*)&qhi[qoff + s * 32 + quad * 8];
                ql[s] = *(const bf16x8*)&qlo[qoff + s * 32 + quad * 8];
            }
        }

        f32x4 o[4];
#pragma unroll
        for (int i = 0; i < 4; ++i) o[i] = (f32x4)0.0f;
        float m_i = -1e30f, l_i = 0.f;

        __syncthreads();   // all waves done reading LDS from previous phase
        stage(0, 0);

        for (int j0 = 0; j0 <= q0; j0 += 64) {
            const int  cur = (j0 >> 6) & 1;
            __syncthreads();            // drains gl2lds(buf[cur]); buf[cur^1] readers done
            if (j0 + 64 <= q0) stage(j0 + 64, cur ^ 1);   // overlaps compute

            const __bf16* Kh = Kh2[cur];
            const __bf16* Kl = Kl2[cur];
            const __bf16* Vt = Vt2[cur];

            // S^T = K Q^T: rows=keys (kc,quad,reg), cols=qrows (l16)
            f32x4 sa[4];
#pragma unroll
            for (int i = 0; i < 4; ++i) sa[i] = (f32x4)0.0f;
#pragma unroll
            for (int s = 0; s < 2; ++s) {
                const int c8s = ((s * 4 + quad) ^ sw) * 8;   // swizzled col
#pragma unroll
                for (int kc = 0; kc < 4; ++kc) {
                    bf16x8 kh = *(const bf16x8*)&Kh[(kc * 16 + l16) * 64 + c8s];
                    bf16x8 kv = *(const bf16x8*)&Kl[(kc * 16 + l16) * 64 + c8s];
                    sa[kc] = mfma16(kh, qh[s], sa[kc]);
                    sa[kc] = mfma16(kv, qh[s], sa[kc]);
                    sa[kc] = mfma16(kh, ql[s], sa[kc]);
                }
            }

            // causal mask + online softmax (cross-quad shfl reductions)
            const int  qr   = q0 + 16 * w + l16;
            const bool need = (j0 + 63 > q0 + 16 * w);
            if (need) {
#pragma unroll
                for (int kc = 0; kc < 4; ++kc)
#pragma unroll
                    for (int r = 0; r < 4; ++r)
                        if (j0 + kc * 16 + quad * 4 + r > qr) sa[kc][r] = -1e30f;
            }
            // depth-4 pairwise max tree (exact; was 15-deep serial chain)
            float t0 = fmaxf(fmaxf(sa[0][0], sa[0][1]), fmaxf(sa[0][2], sa[0][3]));
            float t1 = fmaxf(fmaxf(sa[1][0], sa[1][1]), fmaxf(sa[1][2], sa[1][3]));
            float t2 = fmaxf(fmaxf(sa[2][0], sa[2][1]), fmaxf(sa[2][2], sa[2][3]));
            float t3 = fmaxf(fmaxf(sa[3][0], sa[3][1]), fmaxf(sa[3][2], sa[3][3]));
            float mx = fmaxf(fmaxf(t0, t1), fmaxf(t2, t3));
            mx = fmaxf(mx, __shfl_xor(mx, 16));
            mx = fmaxf(mx, __shfl_xor(mx, 32));
            float mn    = fmaxf(fmaxf(m_i, mx), -1e20f);
            float alpha = exp2f(m_i - mn);
            m_i = mn;
            float rs = 0.f;
            __bf16* pw = &Pw[w][0];
#pragma unroll
            for (int kc = 0; kc < 4; ++kc) {
                float p0 = exp2f(sa[kc][0] - mn);
                float p1 = exp2f(sa[kc][1] - mn);
                float p2 = exp2f(sa[kc][2] - mn);
                float p3 = exp2f(sa[kc][3] - mn);
                rs += (p0 + p1) + (p2 + p3);
                bf16x4 pk = { (__bf16)p0, (__bf16)p1, (__bf16)p2, (__bf16)p3 };
                *(bf16x4*)&pw[l16 * PSP + kc * 16 + quad * 4] = pk;
            }
            rs += __shfl_xor(rs, 16);
            rs += __shfl_xor(rs, 32);
            l_i = l_i * alpha + rs;
#pragma unroll
            for (int dc = 0; dc < 4; ++dc) o[dc] *= alpha;

            // O^T += V^T P^T: rows=d (dc,quad,reg), cols=qrows (l16)
#pragma unroll
            for (int s = 0; s < 2; ++s) {
                const int c8s = ((s * 4 + quad) ^ sw) * 8;
                bf16x8 pb = *(const bf16x8*)&pw[l16 * PSP + s * 32 + quad * 8];
#pragma unroll
                for (int dc = 0; dc < 4; ++dc) {
                    bf16x8 va = *(const bf16x8*)&Vt[(dc * 16 + l16) * 64 + c8s];
                    o[dc] = mfma16(va, pb, o[dc]);
                }
            }
        }

        // epilogue: normalize, transpose via per-wave P buffer, coalesced store
        {
            float   invl = 1.0f / l_i;
            __bf16* pw   = &Pw[w][0];
#pragma unroll
            for (int dc = 0; dc < 4; ++dc) {
                bf16x4 ov = { (__bf16)(o[dc][0] * invl), (__bf16)(o[dc][1] * invl),
                              (__bf16)(o[dc][2] * invl), (__bf16)(o[dc][3] * invl) };
                *(bf16x4*)&pw[l16 * PSP + dc * 16 + quad * 4] = ov;
            }
            const int qrl  = lane >> 2;          // 0..15
            const int dch  = (lane & 3) * 16;    // 0,16,32,48
            const int qrow = q0 + 16 * w + qrl;
            const __bf16* src = &pw[qrl * PSP + dch];
            __bf16*       dst = &yb[(size_t)(b * T_SEQ + qrow) * DM + h * HD + dch];
            *(bf16x8*)dst       = *(const bf16x8*)src;
            *(bf16x8*)(dst + 8) = *(const bf16x8*)(src + 8);
        }
    }
}

extern "C" void kernel_launch(void* const* d_in, const int* in_sizes, int n_in,
                              void* d_out, int out_size, void* d_ws, size_t ws_size,
                              hipStream_t stream)
{
    (void)in_sizes; (void)n_in; (void)out_size; (void)ws_size;

    const float* x   = (const float*)d_in[0];
    const float* Wq  = (const float*)d_in[2];
    const float* bq  = (const float*)d_in[3];
    const float* Wkv = (const float*)d_in[4];
    const float* bkv = (const float*)d_in[5];
    const float* Wk  = (const float*)d_in[6];
    const float* bk  = (const float*)d_in[7];
    const float* Wv  = (const float*)d_in[8];
    const float* bv  = (const float*)d_in[9];
    const float* Wo  = (const float*)d_in[10];
    const float* bo  = (const float*)d_in[11];
    const float* Wkr = (const float*)d_in[12];

    const int    BT = 2 * T_SEQ;   // 4096
    const size_t MB = 1024 * 1024;
    char* base = (char*)d_ws;

    __bf16* xhi    = (__bf16*)(base +  0 * MB);
    __bf16* xlo    = (__bf16*)(base +  8 * MB);
    __bf16* qhi    = (__bf16*)(base + 16 * MB);
    __bf16* qlo    = (__bf16*)(base + 24 * MB);
    __bf16* Wqt_h  = (__bf16*)(base + 32 * MB);
    __bf16* Wqt_l  = (__bf16*)(base + 34 * MB);
    __bf16* Wkvt_h = (__bf16*)(base + 36 * MB);
    __bf16* Wkvt_l = (__bf16*)(base + 37 * MB);
    __bf16* kvhi   = (__bf16*)(base + 38 * MB);
    __bf16* kvlo   = (__bf16*)(base + 40 * MB);
    __bf16* W2t_h  = (__bf16*)(base + 42 * MB);
    __bf16* W2t_l  = (__bf16*)(base + 42 * MB + 512 * 1024);
    __bf16* Wvt    = (__bf16*)(base + 43 * MB);
    __bf16* Wot    = (__bf16*)(base + 43 * MB + 512 * 1024);
    float*  b2     = (float*) (base + 45 * MB + 512 * 1024);
    float2* rtab   = (float2*)(base + 46 * MB);               // 512 KB cos/sin table
    __bf16* vtg    = (__bf16*)(base +  8 * MB);               // overlays xlo (dead after gemm_qkv)
    __bf16* ybb    = (__bf16*)(base +  0 * MB);               // overlays xhi (dead after gemm_qkv)
    __bf16* khi    = (__bf16*)d_out;                          // d_out as scratch
    __bf16* klo    = (__bf16*)d_out + (size_t)BT * DM;        // overwritten by o gemm

    dim3 blk(256);
    prep<<<3972, blk, 0, stream>>>(x, Wq, Wkv, Wv, Wo, Wk, Wkr, bk,
                                   xhi, xlo, Wqt_h, Wqt_l, Wkvt_h, Wkvt_l,
                                   Wvt, Wot, W2t_h, W2t_l, b2, rtab);
    gemm_qkv<<<dim3(10, 32), blk, 0, stream>>>(xhi, xlo, Wqt_h, Wqt_l, bq, rtab, qhi, qlo,
                                               Wkvt_h, Wkvt_l, bkv, kvhi, kvlo);
    gemm_kv2<<<dim3(16, 32), blk, 0, stream>>>(kvhi, kvlo, W2t_h, W2t_l, b2,
                                               khi, klo, Wvt, bv, vtg);
    attn_v9<<<512, blk, 0, stream>>>(qhi, qlo, khi, klo, vtg, ybb);
    gemm_o<<<dim3(8, 32), blk, 0, stream>>>(ybb, Wot, bo, (float*)d_out);
}